// Round 14
// baseline (833.284 us; speedup 1.0000x reference)
//
#include <hip/hip_runtime.h>

// VoiceModel: 2 branches x { scalar-LSTM(1->1,L2) over T=512 per (b,class),
// then LSTM(1->256,L2) over 128 class-steps }, concat -> MLP(512->200->128).
// Round 14: (a) 4-way hidden split -> 256 blocks (128 L0 + 128 L1) at 1/CU,
// 128 KB LDS weight slices, exchange degree 3, round-9 relaxed-sc1 protocol;
// (b) scalar LSTM software-pipelined (L0(t) || L1(t-1)) for 2x ILP.

typedef _Float16 f16;
typedef __attribute__((ext_vector_type(4))) _Float16 f16x4;
typedef __attribute__((ext_vector_type(8))) _Float16 f16x8;
typedef __attribute__((ext_vector_type(4))) float f32x4;
typedef unsigned long long u64;

#define NBATCH 256
#define NTIME  512
#define NCLS   128
#define NHID   256

__device__ __forceinline__ float sigf(float x) {
    return __builtin_amdgcn_rcpf(1.0f + __expf(-x));
}
__device__ __forceinline__ float tanh_f(float x) {
    return fmaf(2.0f, __builtin_amdgcn_rcpf(1.0f + __expf(-2.0f * x)), -1.0f);
}
__device__ __forceinline__ f16x4 LO(f16x8 v) { f16x4 r; r[0]=v[0]; r[1]=v[1]; r[2]=v[2]; r[3]=v[3]; return r; }
__device__ __forceinline__ f16x4 HI(f16x8 v) { f16x4 r; r[0]=v[4]; r[1]=v[5]; r[2]=v[6]; r[3]=v[7]; return r; }

// LLC-coherent (sc1) relaxed agent atomics (proven round 9).
__device__ __forceinline__ u64 ld_llc(const u64* p) {
    return __hip_atomic_load(p, __ATOMIC_RELAXED, __HIP_MEMORY_SCOPE_AGENT);
}
__device__ __forceinline__ void st_llc(u64* p, u64 v) {
    __hip_atomic_store(p, v, __ATOMIC_RELAXED, __HIP_MEMORY_SCOPE_AGENT);
}
__device__ __forceinline__ int ld_flag(const int* p) {
    return __hip_atomic_load(p, __ATOMIC_RELAXED, __HIP_MEMORY_SCOPE_AGENT);
}
__device__ __forceinline__ void st_flag(int* p, int v) {
    __hip_atomic_store(p, v, __ATOMIC_RELAXED, __HIP_MEMORY_SCOPE_AGENT);
}

// ---------------- K0: convert + swizzle 6 weight matrices (1024x256) to f16 --
// layout per matrix: elem ((g*16+fi)*8+ktp)*512 + l*8 + e   (l = lane)
//   = W[g*256 + fi*16 + fr][ktp*32 + (e>>2)*16 + fq*4 + (e&3)]
struct P6 {
    const float* s0; const float* s1; const float* s2;
    const float* s3; const float* s4; const float* s5;
};

__global__ __launch_bounds__(256) void k_cvt(P6 p, f16* __restrict__ dst) {
    int i = blockIdx.x * 256 + threadIdx.x;      // 6 * 262144 total
    int seg = i >> 18, d = i & 262143;
    const float* s = seg == 0 ? p.s0 : seg == 1 ? p.s1 : seg == 2 ? p.s2
                   : seg == 3 ? p.s3 : seg == 4 ? p.s4 : p.s5;
    const int e  = d & 7;
    const int fr = (d >> 3) & 15;
    const int fq = (d >> 7) & 3;
    const int ktp = (d >> 9) & 7;
    const int fi = (d >> 12) & 15;
    const int g  = (d >> 16) & 3;
    const int row = g * 256 + fi * 16 + fr;
    const int col = ktp * 32 + (e >> 2) * 16 + fq * 4 + (e & 3);
    dst[i] = (f16)s[row * 256 + col];
}

// ---------------- zero the exchange flags (every call; graph-replay safe) ----
__global__ void k_zero(int* __restrict__ f) { f[blockIdx.x * 1024 + threadIdx.x] = 0; }

// ---------------- K1: scalar 2-layer LSTM, software-pipelined ----------------
// Iteration t computes L0(t) and L1(t-1) concurrently (both depend only on
// h0(t-1)): 2x ILP on the latency-bound chain. Per-cell math identical to the
// sequential form (bit-identical results).
__global__ __launch_bounds__(128) void k_scalar_lstm(
    const int* __restrict__ ln, const int* __restrict__ rn,
    const float* __restrict__ tlW, const float* __restrict__ tlU, const float* __restrict__ tlb,
    const float* __restrict__ trW, const float* __restrict__ trU, const float* __restrict__ trb,
    float* __restrict__ states)
{
    __shared__ int tok[NTIME];
    const int bid = blockIdx.x;
    const int branch = bid >> 8;
    const int b = bid & 255;
    const int* tp = (branch ? rn : ln) + (size_t)b * (4 * NTIME);  // voice 0
    for (int i = threadIdx.x; i < NTIME; i += 128) tok[i] = tp[i];
    __syncthreads();
    const float* W  = branch ? trW : tlW;
    const float* U  = branch ? trU : tlU;
    const float* Bb = branch ? trb : tlb;
    const float u00 = U[0], u01 = U[1], u02 = U[2], u03 = U[3];
    const float f00 = Bb[0], f01 = Bb[1], f02 = Bb[2], f03 = Bb[3];
    const float o00 = f00 + W[0], o01 = f01 + W[1], o02 = f02 + W[2], o03 = f03 + W[3];
    const float w10 = W[4], w11 = W[5], w12 = W[6], w13 = W[7];
    const float u10 = U[4], u11 = U[5], u12 = U[6], u13 = U[7];
    const float b10 = Bb[4], b11 = Bb[5], b12 = Bb[6], b13 = Bb[7];
    const int n = threadIdx.x;
    float h0 = 0.f, c0 = 0.f, h1 = 0.f, c1 = 0.f;
    {   // L0 step 0
        const bool x = (tok[0] == n);
        float pi = fmaf(u00, h0, x ? o00 : f00);
        float pf = fmaf(u01, h0, x ? o01 : f01);
        float pg = fmaf(u02, h0, x ? o02 : f02);
        float po = fmaf(u03, h0, x ? o03 : f03);
        const float ig = sigf(pi), fg = sigf(pf), gg = tanh_f(pg), og = sigf(po);
        c0 = fmaf(fg, c0, ig * gg);
        h0 = og * tanh_f(c0);
    }
    for (int t = 1; t < NTIME; ++t) {
        const bool x = (tok[t] == n);
        // L0(t): reads h0(t-1)
        float api = fmaf(u00, h0, x ? o00 : f00);
        float apf = fmaf(u01, h0, x ? o01 : f01);
        float apg = fmaf(u02, h0, x ? o02 : f02);
        float apo = fmaf(u03, h0, x ? o03 : f03);
        // L1(t-1): reads h0(t-1), h1(t-2) — independent of L0(t)
        float bpi = fmaf(w10, h0, fmaf(u10, h1, b10));
        float bpf = fmaf(w11, h0, fmaf(u11, h1, b11));
        float bpg = fmaf(w12, h0, fmaf(u12, h1, b12));
        float bpo = fmaf(w13, h0, fmaf(u13, h1, b13));
        const float aig = sigf(api), afg = sigf(apf), agg = tanh_f(apg), aog = sigf(apo);
        const float big = sigf(bpi), bfg = sigf(bpf), bgg = tanh_f(bpg), bog = sigf(bpo);
        c0 = fmaf(afg, c0, aig * agg);
        c1 = fmaf(bfg, c1, big * bgg);
        h0 = aog * tanh_f(c0);
        h1 = bog * tanh_f(c1);
    }
    {   // final L1 step (t = NTIME-1)
        float pi = fmaf(w10, h0, fmaf(u10, h1, b10));
        float pf = fmaf(w11, h0, fmaf(u11, h1, b11));
        float pg = fmaf(w12, h0, fmaf(u12, h1, b12));
        float po = fmaf(w13, h0, fmaf(u13, h1, b13));
        const float ig = sigf(pi), fg = sigf(pf), gg = tanh_f(pg), og = sigf(po);
        c1 = fmaf(fg, c1, ig * gg);
        h1 = og * tanh_f(c1);
    }
    states[((size_t)(branch * NBATCH + b)) * NCLS + n] = h1;
}

// ---------------- K2: pipelined L0+L1 recurrence, 4-way split (256 blocks) ---
// blocks 0-127: layer 0; blocks 128-255: layer 1. sub = bid (or bid-128);
// qm = sub>>5 in [0,4) (member, owns 64 hidden units), g = sub&31 (group).
// 4 waves = 4 gates; wave w also finishes local frag w (fi = qm*4+w).
// Exchange: 2 KB chunks, 3 peers, round-9 relaxed-sc1 + padded-flag protocol.
// L1 consumes h0img[g][t] gated by monotonic flags0 (lag-1 pipeline).
__global__ __launch_bounds__(256, 1) void k_rec(
    const float* __restrict__ states,
    const f16* __restrict__ whh0, const f16* __restrict__ whh1,
    const f16* __restrict__ wih1,
    const float* __restrict__ wih0L, const float* __restrict__ wih0R,
    const float* __restrict__ b0L, const float* __restrict__ b0R,
    const float* __restrict__ b1L, const float* __restrict__ b1R,
    f16* __restrict__ h0img,               // [32 group][128 s][4096]
    f16* __restrict__ ring,                // [32 group][4 slot][4096]
    int* __restrict__ flags0,              // [32 group][4] stride 64 ints
    int* __restrict__ flags1,              // [32 group][4] stride 64 ints
    float* __restrict__ h1out)             // [2][256][256] f32
{
    extern __shared__ char smem[];
    f16*   wlds = (f16*)smem;                    // 131072 B weight slice
    f16*   img  = (f16*)(smem + 131072);         // 8192 B h image
    float* cmb  = (float*)(smem + 139264);       // 16384 B (total 155648)

    const int bid = blockIdx.x;
    const bool isL1 = bid >= 128;
    const int sub = isL1 ? bid - 128 : bid;
    const int qm = sub >> 5, g = sub & 31;
    const int branch = g >> 4, tb = g & 15;
    const int tid = threadIdx.x;
    const int w = tid >> 6, l = tid & 63, fr = l & 15, fq = l >> 4;
    const int fi = qm * 4 + w;                   // this wave's finisher frag

    {   // stage weight slice: 128 rows (gate g4, local frag j, ktp) x 512 f16
        const f16* base = (isL1 ? whh1 : whh0) + ((size_t)branch << 18);
        for (int c = tid; c < 8192; c += 256) {
            const int rl = c >> 6, coli = c & 63;
            const int gs4 = rl >> 5, j = (rl >> 3) & 3, ktp = rl & 7;
            *(uint4*)(wlds + rl * 512 + coli * 8) =
                *(const uint4*)(base + ((size_t)((gs4 * 16 + qm * 4 + j) * 8 + ktp) << 9) + coli * 8);
        }
    }
    ((uint4*)img)[tid] = (uint4){0u, 0u, 0u, 0u};
    ((uint4*)img)[tid + 256] = (uint4){0u, 0u, 0u, 0u};

    float bv[4], w0v[4];
    {
        const float* bias = isL1 ? (branch ? b1R : b1L) : (branch ? b0R : b0L);
        const float* w0p  = branch ? wih0R : wih0L;
#pragma unroll
        for (int g4 = 0; g4 < 4; ++g4) {
            bv[g4]  = bias[g4 * 256 + fi * 16 + fr];
            w0v[g4] = isL1 ? 0.f : w0p[g4 * 256 + fi * 16 + fr];
        }
    }
    float cst[4] = {0.f, 0.f, 0.f, 0.f};

    if (!isL1) {
        // ================= LAYER 0 =================
        f16* gimg = h0img + (size_t)g * (NCLS * 4096);
        int* f0 = flags0 + g * 256;
        __syncthreads();
        for (int s = 0; s < NCLS; ++s) {
            float st[4];
#pragma unroll
            for (int r = 0; r < 4; ++r)
                st[r] = states[((size_t)(branch * NBATCH + tb * 16 + fq * 4 + r)) * NCLS + s];
            f16x4 af[16];
#pragma unroll
            for (int kt = 0; kt < 16; ++kt)
                af[kt] = *(const f16x4*)(img + kt * 256 + l * 4);
            f32x4 acc[4];
#pragma unroll
            for (int j = 0; j < 4; ++j) { f32x4 z = {0.f,0.f,0.f,0.f}; acc[j] = z; }
#pragma unroll
            for (int j = 0; j < 4; ++j)
#pragma unroll
                for (int ktp = 0; ktp < 8; ++ktp) {
                    const f16x8 v = *(const f16x8*)(wlds + (((w * 4 + j) * 8 + ktp) << 9) + l * 8);
                    acc[j] = __builtin_amdgcn_mfma_f32_16x16x16f16(af[2*ktp],   LO(v), acc[j], 0, 0, 0);
                    acc[j] = __builtin_amdgcn_mfma_f32_16x16x16f16(af[2*ktp+1], HI(v), acc[j], 0, 0, 0);
                }
#pragma unroll
            for (int j = 0; j < 4; ++j)
                if (j != w)
#pragma unroll
                    for (int r = 0; r < 4; ++r)
                        cmb[((w * 4 + j) * 4 + r) * 64 + l] = acc[j][r];
            __syncthreads();                // cmb ready; img reads done
#pragma unroll
            for (int r = 0; r < 4; ++r) {   // finish frag fi (wave w)
                float gv[4];
#pragma unroll
                for (int g4 = 0; g4 < 4; ++g4)
                    gv[g4] = (g4 == w) ? acc[w][r] : cmb[((g4 * 4 + w) * 4 + r) * 64 + l];
                const float pi = fmaf(st[r], w0v[0], gv[0] + bv[0]);
                const float pf = fmaf(st[r], w0v[1], gv[1] + bv[1]);
                const float pg = fmaf(st[r], w0v[2], gv[2] + bv[2]);
                const float po = fmaf(st[r], w0v[3], gv[3] + bv[3]);
                const float ig = sigf(pi), fg = sigf(pf), gg = tanh_f(pg), og = sigf(po);
                cst[r] = fmaf(fg, cst[r], ig * gg);
                const float hn = og * tanh_f(cst[r]);
                img[fi * 256 + (fq * 4 + r + 16 * (fr >> 2)) * 4 + (fr & 3)] = (f16)hn;
            }
            __syncthreads();                // own 2 KB chunk complete in LDS
            if (w == 0) {
                u64* gd = (u64*)(gimg + (size_t)s * 4096) + qm * 256;
                const u64* sc = (const u64*)img + qm * 256;
                st_llc(gd + l,       sc[l]);
                st_llc(gd + 64 + l,  sc[64 + l]);
                st_llc(gd + 128 + l, sc[128 + l]);
                st_llc(gd + 192 + l, sc[192 + l]);
                asm volatile("s_waitcnt vmcnt(0)" ::: "memory");
                if (l == 0) st_flag(f0 + qm * 64, s + 1);
                if (s < NCLS - 1 && l < 3) {
                    const int p = l + (l >= qm);
                    while (ld_flag(f0 + p * 64) <= s) __builtin_amdgcn_s_sleep(1);
                }
            }
            if (s == NCLS - 1) break;
            __syncthreads();                // peers ready
            if (tid < 192) {                // gather 3 peer chunks (6 KB)
                const int j = tid >> 6, o = tid & 63;
                const int p = j + (j >= qm);
                const u64* gs = (const u64*)(gimg + (size_t)s * 4096) + p * 256;
                u64 t0 = ld_llc(gs + o),       t1 = ld_llc(gs + 64 + o),
                    t2 = ld_llc(gs + 128 + o), t3 = ld_llc(gs + 192 + o);
                u64* di = (u64*)img + p * 256;
                di[o] = t0; di[64 + o] = t1; di[128 + o] = t2; di[192 + o] = t3;
            }
            __syncthreads();                // img(s) complete
        }
    } else {
        // ================= LAYER 1 =================
        const f16* wstream = wih1 + ((size_t)branch << 18) + l * 8;
        const f16* gimg = h0img + (size_t)g * (NCLS * 4096);
        f16* gring = ring + (size_t)g * (4 * 4096);
        int* f0 = flags0 + g * 256;
        int* f1 = flags1 + g * 256;
        __syncthreads();
        if (w == 1 && l < 4)                // wait for h0(0) (4 producers)
            while (ld_flag(f0 + l * 64) < 1) __builtin_amdgcn_s_sleep(2);
        __syncthreads();
        f16x4 af0[16];
        {
            const u64* s2 = (const u64*)gimg + l;
#pragma unroll
            for (int kt = 0; kt < 16; ++kt)
                af0[kt] = __builtin_bit_cast(f16x4, ld_llc(s2 + kt * 64));
        }
        for (int t = 0; t < NCLS; ++t) {
            f16x4 af1[16];
#pragma unroll
            for (int kt = 0; kt < 16; ++kt)
                af1[kt] = *(const f16x4*)(img + kt * 256 + l * 4);
            f32x4 acc[4];
#pragma unroll
            for (int j = 0; j < 4; ++j) { f32x4 z = {0.f,0.f,0.f,0.f}; acc[j] = z; }
#pragma unroll
            for (int j = 0; j < 4; ++j) {
                f16x8 wv[8];                // stream Wih1 rows (L2-resident)
#pragma unroll
                for (int ktp = 0; ktp < 8; ++ktp)
                    wv[ktp] = *(const f16x8*)(wstream
                        + ((size_t)((w * 16 + qm * 4 + j) * 8 + ktp) << 9));
#pragma unroll
                for (int ktp = 0; ktp < 8; ++ktp) {
                    const f16x8 v = *(const f16x8*)(wlds + (((w * 4 + j) * 8 + ktp) << 9) + l * 8);
                    acc[j] = __builtin_amdgcn_mfma_f32_16x16x16f16(af1[2*ktp],   LO(v), acc[j], 0, 0, 0);
                    acc[j] = __builtin_amdgcn_mfma_f32_16x16x16f16(af1[2*ktp+1], HI(v), acc[j], 0, 0, 0);
                }
#pragma unroll
                for (int ktp = 0; ktp < 8; ++ktp) {
                    acc[j] = __builtin_amdgcn_mfma_f32_16x16x16f16(af0[2*ktp],   LO(wv[ktp]), acc[j], 0, 0, 0);
                    acc[j] = __builtin_amdgcn_mfma_f32_16x16x16f16(af0[2*ktp+1], HI(wv[ktp]), acc[j], 0, 0, 0);
                }
            }
#pragma unroll
            for (int j = 0; j < 4; ++j)
                if (j != w)
#pragma unroll
                    for (int r = 0; r < 4; ++r)
                        cmb[((w * 4 + j) * 4 + r) * 64 + l] = acc[j][r];
            __syncthreads();                // cmb ready; img reads done
#pragma unroll
            for (int r = 0; r < 4; ++r) {   // finish frag fi (wave w)
                float gv[4];
#pragma unroll
                for (int g4 = 0; g4 < 4; ++g4)
                    gv[g4] = (g4 == w) ? acc[w][r] : cmb[((g4 * 4 + w) * 4 + r) * 64 + l];
                const float pi = gv[0] + bv[0];
                const float pf = gv[1] + bv[1];
                const float pg = gv[2] + bv[2];
                const float po = gv[3] + bv[3];
                const float ig = sigf(pi), fg = sigf(pf), gg = tanh_f(pg), og = sigf(po);
                cst[r] = fmaf(fg, cst[r], ig * gg);
                const float hn = og * tanh_f(cst[r]);
                if (t == NCLS - 1)
                    h1out[((size_t)(branch * NBATCH + tb * 16 + fq * 4 + r)) * NHID
                          + fi * 16 + fr] = hn;
                else
                    img[fi * 256 + (fq * 4 + r + 16 * (fr >> 2)) * 4 + (fr & 3)] = (f16)hn;
            }
            if (t == NCLS - 1) break;
            __syncthreads();                // own 2 KB chunk complete in LDS
            f16* slot = gring + (size_t)(t & 3) * 4096;
            if (w == 0) {
                u64* gd = (u64*)slot + qm * 256;
                const u64* sc = (const u64*)img + qm * 256;
                st_llc(gd + l,       sc[l]);
                st_llc(gd + 64 + l,  sc[64 + l]);
                st_llc(gd + 128 + l, sc[128 + l]);
                st_llc(gd + 192 + l, sc[192 + l]);
                asm volatile("s_waitcnt vmcnt(0)" ::: "memory");
                if (l == 0) st_flag(f1 + qm * 64, t + 1);
                if (l < 3) {
                    const int p = l + (l >= qm);
                    while (ld_flag(f1 + p * 64) <= t) __builtin_amdgcn_s_sleep(1);
                }
            }
            if (w == 1 && l < 4)            // h0(t+1) ready? (flags0 monotonic)
                while (ld_flag(f0 + l * 64) < t + 2) __builtin_amdgcn_s_sleep(1);
            __syncthreads();                // peers + h0(t+1) ready
            {                               // prefetch h0(t+1) frags
                const u64* s2 = (const u64*)(gimg + (size_t)(t + 1) * 4096) + l;
#pragma unroll
                for (int kt = 0; kt < 16; ++kt)
                    af0[kt] = __builtin_bit_cast(f16x4, ld_llc(s2 + kt * 64));
            }
            if (tid < 192) {                // gather 3 peer h1 chunks (6 KB)
                const int j = tid >> 6, o = tid & 63;
                const int p = j + (j >= qm);
                const u64* gs = (const u64*)slot + p * 256;
                u64 t0 = ld_llc(gs + o),       t1 = ld_llc(gs + 64 + o),
                    t2 = ld_llc(gs + 128 + o), t3 = ld_llc(gs + 192 + o);
                u64* di = (u64*)img + p * 256;
                di[o] = t0; di[64 + o] = t1; di[128 + o] = t2; di[192 + o] = t3;
            }
            __syncthreads();                // img(t) complete
        }
    }
}

// ---------------- K4: MLP head (2H -> 200 -> 128), f32 ------------------------
__global__ __launch_bounds__(256) void k_mlp(
    const float* __restrict__ h1all,   // [2][256][256]
    const float* __restrict__ W1, const float* __restrict__ b1,
    const float* __restrict__ W2, const float* __restrict__ b2,
    float* __restrict__ out)
{
    __shared__ float hrow[512];
    __shared__ float hid[200];
    const int b = blockIdx.x, tid = threadIdx.x;
    hrow[tid]       = h1all[(size_t)b * NHID + tid];
    hrow[256 + tid] = h1all[(size_t)(NBATCH + b) * NHID + tid];
    __syncthreads();
    if (tid < 200) {
        float a = b1[tid];
        const float* wr = W1 + (size_t)tid * 512;
        for (int k = 0; k < 512; ++k) a = fmaf(wr[k], hrow[k], a);
        hid[tid] = fmaxf(a, 0.f);
    }
    __syncthreads();
    if (tid < 128) {
        float a = b2[tid];
        const float* wr = W2 + (size_t)tid * 200;
        for (int j = 0; j < 200; ++j) a = fmaf(wr[j], hid[j], a);
        out[(size_t)b * 128 + tid] = a;
    }
}

// ---------------- launch ------------------------------------------------------
extern "C" void kernel_launch(void* const* d_in, const int* in_sizes, int n_in,
                              void* d_out, int out_size, void* d_ws, size_t ws_size,
                              hipStream_t stream)
{
    (void)in_sizes; (void)n_in; (void)out_size; (void)ws_size;
    const int*   ln    = (const int*)d_in[0];
    const int*   rn    = (const int*)d_in[2];
    const float* tlW   = (const float*)d_in[4];
    const float* tlU   = (const float*)d_in[5];
    const float* tlb   = (const float*)d_in[6];
    const float* trW   = (const float*)d_in[7];
    const float* trU   = (const float*)d_in[8];
    const float* trb   = (const float*)d_in[9];
    const float* wih0L = (const float*)d_in[10];
    const float* b0L   = (const float*)d_in[12];
    const float* b1L   = (const float*)d_in[15];
    const float* wih0R = (const float*)d_in[16];
    const float* b0R   = (const float*)d_in[18];
    const float* b1R   = (const float*)d_in[21];
    const float* mW1   = (const float*)d_in[22];
    const float* mb1   = (const float*)d_in[23];
    const float* mW2   = (const float*)d_in[24];
    const float* mb2   = (const float*)d_in[25];

    // workspace layout (bytes)
    char* ws = (char*)d_ws;
    f16*   w16    = (f16*)ws;                        // 3 MB swizzled weights
    float* states = (float*)(ws + 3145728);          // 256 KB
    float* h1out  = (float*)(ws + 3407872);          // 512 KB
    int*   flags  = (int*)(ws + 3932160);            // 64 KB (2 x 32 x 4 x 64 ints)
    f16*   ring   = (f16*)(ws + 4063232);            // 1 MB (32 x 4 x 4096 f16)
    f16*   h0img  = (f16*)(ws + 5111808);            // 32 MB (32 x 128 x 4096 f16)

    f16* whh0 = w16;
    f16* whh1 = w16 + 2 * 262144;
    f16* wih1 = w16 + 4 * 262144;
    int* flags0 = flags;
    int* flags1 = flags + 8192;

    (void)hipFuncSetAttribute(reinterpret_cast<const void*>(k_rec),
                              hipFuncAttributeMaxDynamicSharedMemorySize, 155648);

    P6 p { (const float*)d_in[11], (const float*)d_in[17],   // nl_Whh0, nr_Whh0
           (const float*)d_in[14], (const float*)d_in[20],   // nl_Whh1, nr_Whh1
           (const float*)d_in[13], (const float*)d_in[19] }; // nl_Wih1, nr_Wih1
    k_zero<<<16, 1024, 0, stream>>>(flags);
    k_cvt<<<6144, 256, 0, stream>>>(p, w16);
    k_scalar_lstm<<<512, 128, 0, stream>>>(ln, rn, tlW, tlU, tlb, trW, trU, trb, states);
    k_rec<<<256, 256, 155648, stream>>>(states, whh0, whh1, wih1, wih0L, wih0R,
                                        b0L, b0R, b1L, b1R, h0img, ring,
                                        flags0, flags1, h1out);
    k_mlp<<<256, 256, 0, stream>>>(h1out, mW1, mb1, mW2, mb2, (float*)d_out);
}

// Round 15
// 640.122 us; speedup vs baseline: 1.3018x; 1.3018x over previous
//
#include <hip/hip_runtime.h>

// VoiceModel: 2 branches x { scalar-LSTM(1->1,L2) over T=512 per (b,class),
// then LSTM(1->256,L2) over 128 class-steps }, concat -> MLP(512->200->128).
// Round 15: consolidation. k_rec = round-13 verbatim (best measured, 540us:
// 8-way split, L0/L1 pipelined across 512 blocks, relaxed-sc1 exchange).
// Preamble fused into ONE kernel (scalar-LSTM || weight-cvt || flag-zero).

typedef _Float16 f16;
typedef __attribute__((ext_vector_type(4))) _Float16 f16x4;
typedef __attribute__((ext_vector_type(8))) _Float16 f16x8;
typedef __attribute__((ext_vector_type(4))) float f32x4;
typedef unsigned long long u64;

#define NBATCH 256
#define NTIME  512
#define NCLS   128
#define NHID   256

__device__ __forceinline__ float sigf(float x) {
    return __builtin_amdgcn_rcpf(1.0f + __expf(-x));
}
__device__ __forceinline__ float tanh_f(float x) {
    return fmaf(2.0f, __builtin_amdgcn_rcpf(1.0f + __expf(-2.0f * x)), -1.0f);
}
__device__ __forceinline__ f16x4 LO(f16x8 v) { f16x4 r; r[0]=v[0]; r[1]=v[1]; r[2]=v[2]; r[3]=v[3]; return r; }
__device__ __forceinline__ f16x4 HI(f16x8 v) { f16x4 r; r[0]=v[4]; r[1]=v[5]; r[2]=v[6]; r[3]=v[7]; return r; }

// LLC-coherent (sc1) relaxed agent atomics (proven round 9).
__device__ __forceinline__ u64 ld_llc(const u64* p) {
    return __hip_atomic_load(p, __ATOMIC_RELAXED, __HIP_MEMORY_SCOPE_AGENT);
}
__device__ __forceinline__ void st_llc(u64* p, u64 v) {
    __hip_atomic_store(p, v, __ATOMIC_RELAXED, __HIP_MEMORY_SCOPE_AGENT);
}
__device__ __forceinline__ int ld_flag(const int* p) {
    return __hip_atomic_load(p, __ATOMIC_RELAXED, __HIP_MEMORY_SCOPE_AGENT);
}
__device__ __forceinline__ void st_flag(int* p, int v) {
    __hip_atomic_store(p, v, __ATOMIC_RELAXED, __HIP_MEMORY_SCOPE_AGENT);
}

struct P6 {
    const float* s0; const float* s1; const float* s2;
    const float* s3; const float* s4; const float* s5;
};

// ---------------- K_PRE: fused {scalar-LSTM | weight cvt+swizzle | flag zero} --
// grid 770 x 256 thr:
//   blocks 0-255 : scalar 2-layer LSTM, 2 (branch,b) chains per block
//                  (software-pipelined L0(t) || L1(t-1), 2x ILP)
//   blocks 256-767: convert+swizzle 6 weight matrices (3072 elems each)
//   blocks 768-769: zero the 128 KB flag region
// cvt layout per matrix: elem ((g*16+fi)*8+ktp)*512 + l*8 + e
//   = W[g*256 + fi*16 + fr][ktp*32 + (e>>2)*16 + fq*4 + (e&3)]
__global__ __launch_bounds__(256) void k_pre(
    const int* __restrict__ ln, const int* __restrict__ rn,
    const float* __restrict__ tlW, const float* __restrict__ tlU, const float* __restrict__ tlb,
    const float* __restrict__ trW, const float* __restrict__ trU, const float* __restrict__ trb,
    float* __restrict__ states,
    P6 p, f16* __restrict__ wdst,
    int* __restrict__ flags)
{
    const int bid = blockIdx.x;
    const int tid = threadIdx.x;
    if (bid >= 768) {                      // ---- flag zero ----
        int* f = flags + (bid - 768) * 16384;
        for (int i = tid; i < 16384; i += 256) f[i] = 0;
        return;
    }
    if (bid >= 256) {                      // ---- weight cvt ----
        const int base = (bid - 256) * 3072;
#pragma unroll
        for (int k = 0; k < 12; ++k) {
            const int i = base + k * 256 + tid;
            const int seg = i >> 18, d = i & 262143;
            const float* s = seg == 0 ? p.s0 : seg == 1 ? p.s1 : seg == 2 ? p.s2
                           : seg == 3 ? p.s3 : seg == 4 ? p.s4 : p.s5;
            const int e  = d & 7;
            const int fr = (d >> 3) & 15;
            const int fq = (d >> 7) & 3;
            const int ktp = (d >> 9) & 7;
            const int fi = (d >> 12) & 15;
            const int g  = (d >> 16) & 3;
            const int row = g * 256 + fi * 16 + fr;
            const int col = ktp * 32 + (e >> 2) * 16 + fq * 4 + (e & 3);
            wdst[i] = (f16)s[row * 256 + col];
        }
        return;
    }
    // ---- scalar LSTM: 2 chains per block ----
    __shared__ int tok[2][NTIME];
    const int half = tid >> 7, n = tid & 127;
    const int pair = bid * 2 + half;
    const int branch = pair >> 8;
    const int b = pair & 255;
    const int* tp = (branch ? rn : ln) + (size_t)b * (4 * NTIME);  // voice 0
    for (int i = n; i < NTIME; i += 128) tok[half][i] = tp[i];
    __syncthreads();
    const float* W  = branch ? trW : tlW;
    const float* U  = branch ? trU : tlU;
    const float* Bb = branch ? trb : tlb;
    const float u00 = U[0], u01 = U[1], u02 = U[2], u03 = U[3];
    const float f00 = Bb[0], f01 = Bb[1], f02 = Bb[2], f03 = Bb[3];
    const float o00 = f00 + W[0], o01 = f01 + W[1], o02 = f02 + W[2], o03 = f03 + W[3];
    const float w10 = W[4], w11 = W[5], w12 = W[6], w13 = W[7];
    const float u10 = U[4], u11 = U[5], u12 = U[6], u13 = U[7];
    const float b10 = Bb[4], b11 = Bb[5], b12 = Bb[6], b13 = Bb[7];
    float h0 = 0.f, c0 = 0.f, h1 = 0.f, c1 = 0.f;
    {   // L0 step 0
        const bool x = (tok[half][0] == n);
        float pi = fmaf(u00, h0, x ? o00 : f00);
        float pf = fmaf(u01, h0, x ? o01 : f01);
        float pg = fmaf(u02, h0, x ? o02 : f02);
        float po = fmaf(u03, h0, x ? o03 : f03);
        const float ig = sigf(pi), fg = sigf(pf), gg = tanh_f(pg), og = sigf(po);
        c0 = fmaf(fg, c0, ig * gg);
        h0 = og * tanh_f(c0);
    }
    for (int t = 1; t < NTIME; ++t) {      // L0(t) || L1(t-1): 2x ILP
        const bool x = (tok[half][t] == n);
        float api = fmaf(u00, h0, x ? o00 : f00);
        float apf = fmaf(u01, h0, x ? o01 : f01);
        float apg = fmaf(u02, h0, x ? o02 : f02);
        float apo = fmaf(u03, h0, x ? o03 : f03);
        float bpi = fmaf(w10, h0, fmaf(u10, h1, b10));
        float bpf = fmaf(w11, h0, fmaf(u11, h1, b11));
        float bpg = fmaf(w12, h0, fmaf(u12, h1, b12));
        float bpo = fmaf(w13, h0, fmaf(u13, h1, b13));
        const float aig = sigf(api), afg = sigf(apf), agg = tanh_f(apg), aog = sigf(apo);
        const float big = sigf(bpi), bfg = sigf(bpf), bgg = tanh_f(bpg), bog = sigf(bpo);
        c0 = fmaf(afg, c0, aig * agg);
        c1 = fmaf(bfg, c1, big * bgg);
        h0 = aog * tanh_f(c0);
        h1 = bog * tanh_f(c1);
    }
    {   // final L1 step
        float pi = fmaf(w10, h0, fmaf(u10, h1, b10));
        float pf = fmaf(w11, h0, fmaf(u11, h1, b11));
        float pg = fmaf(w12, h0, fmaf(u12, h1, b12));
        float po = fmaf(w13, h0, fmaf(u13, h1, b13));
        const float ig = sigf(pi), fg = sigf(pf), gg = tanh_f(pg), og = sigf(po);
        c1 = fmaf(fg, c1, ig * gg);
        h1 = og * tanh_f(c1);
    }
    states[((size_t)(branch * NBATCH + b)) * NCLS + n] = h1;
}

// ---------------- K2: pipelined L0+L1 recurrence (512 blocks) ----------------
// (round-13 verbatim — best measured configuration)
// blocks 0-255: layer 0 (group g = bid&31, member qm = bid>>5). 4 waves = gates.
// blocks 256-511: layer 1 (same mapping on bid-256). 4 waves = gates; each wave
// computes Whh1 (LDS) + Wih1 (L2 stream) for both frags; wave 0 finishes.
// L1 consumes h0img[g][t] gated by flags0 (monotonic); lag-1 pipeline.
__global__ __launch_bounds__(256, 2) void k_rec(
    const float* __restrict__ states,
    const f16* __restrict__ whh0, const f16* __restrict__ whh1,
    const f16* __restrict__ wih1,
    const float* __restrict__ wih0L, const float* __restrict__ wih0R,
    const float* __restrict__ b0L, const float* __restrict__ b0R,
    const float* __restrict__ b1L, const float* __restrict__ b1R,
    f16* __restrict__ h0img,               // [32 group][128 s][4096]
    f16* __restrict__ ring,                // [32 group][4 slot][4096]
    int* __restrict__ flags0,              // [32 group][8] stride 64 ints
    int* __restrict__ flags1,              // [32 group][8] stride 64 ints
    float* __restrict__ h1out)             // [2][256][256] f32
{
    extern __shared__ char smem[];
    f16*   wlds = (f16*)smem;                    // 65536 B weight slice
    f16*   img  = (f16*)(smem + 65536);          // 8192 B h image
    float* cmb  = (float*)(smem + 73728);        // 6144 B  (total 79872)

    const int bid = blockIdx.x;
    const bool isL1 = bid >= 256;
    const int sub = isL1 ? (bid - 256) : bid;
    const int qm = sub >> 5, g = sub & 31;
    const int branch = g >> 4, tb = g & 15;
    const int tid = threadIdx.x;
    const int w = tid >> 6, l = tid & 63, fr = l & 15, fq = l >> 4;

    {   // stage the recurrent weight slice (Whh0 or Whh1): 64 rows x 512 f16
        const f16* base = (isL1 ? whh1 : whh0) + ((size_t)branch << 18);
        for (int c = tid; c < 4096; c += 256) {
            const int rl = c >> 6, coli = c & 63;
            const int gg = rl >> 4, ff = (rl >> 3) & 1, ktp = rl & 7;
            *(uint4*)(wlds + rl * 512 + coli * 8) =
                *(const uint4*)(base + ((size_t)((gg * 16 + qm * 2 + ff) * 8 + ktp) << 9) + coli * 8);
        }
    }
    ((uint4*)img)[tid] = (uint4){0u, 0u, 0u, 0u};
    ((uint4*)img)[tid + 256] = (uint4){0u, 0u, 0u, 0u};

    if (!isL1) {
        // ================= LAYER 0 =================
        const float* bias = branch ? b0R : b0L;
        const float* w0p  = branch ? wih0R : wih0L;
        const int fi_f = qm * 2 + (w < 2 ? w : 0);
        float bv[4], w0v[4];
#pragma unroll
        for (int g4 = 0; g4 < 4; ++g4) {
            bv[g4]  = bias[g4 * 256 + fi_f * 16 + fr];
            w0v[g4] = w0p[g4 * 256 + fi_f * 16 + fr];
        }
        float cst[4] = {0.f, 0.f, 0.f, 0.f};
        f16* gimg = h0img + (size_t)g * (NCLS * 4096);
        int* f0 = flags0 + g * 512;
        __syncthreads();

        for (int s = 0; s < NCLS; ++s) {
            float st[4];
            if (w < 2) {
#pragma unroll
                for (int r = 0; r < 4; ++r)
                    st[r] = states[((size_t)(branch * NBATCH + tb * 16 + fq * 4 + r)) * NCLS + s];
            }
            f16x4 af[16];
#pragma unroll
            for (int kt = 0; kt < 16; ++kt)
                af[kt] = *(const f16x4*)(img + kt * 256 + l * 4);
            f32x4 acc[2];
#pragma unroll
            for (int f = 0; f < 2; ++f) {
                f32x4 a0 = {0.f,0.f,0.f,0.f}, a1 = {0.f,0.f,0.f,0.f};
#pragma unroll
                for (int ktp = 0; ktp < 8; ++ktp) {
                    const f16x8 v = *(const f16x8*)(wlds + (((w * 2 + f) * 8 + ktp) << 9) + l * 8);
                    a0 = __builtin_amdgcn_mfma_f32_16x16x16f16(af[2 * ktp],     LO(v), a0, 0, 0, 0);
                    a1 = __builtin_amdgcn_mfma_f32_16x16x16f16(af[2 * ktp + 1], HI(v), a1, 0, 0, 0);
                }
                acc[f] = a0 + a1;
            }
            // publish: e0=(w0,f1) e1=(w1,f0) e2=(w2,f0) e3=(w2,f1) e4=(w3,f0) e5=(w3,f1)
            if (w == 0) {
#pragma unroll
                for (int r = 0; r < 4; ++r) cmb[(0 * 4 + r) * 64 + l] = acc[1][r];
            } else if (w == 1) {
#pragma unroll
                for (int r = 0; r < 4; ++r) cmb[(1 * 4 + r) * 64 + l] = acc[0][r];
            } else if (w == 2) {
#pragma unroll
                for (int r = 0; r < 4; ++r) {
                    cmb[(2 * 4 + r) * 64 + l] = acc[0][r];
                    cmb[(3 * 4 + r) * 64 + l] = acc[1][r];
                }
            } else {
#pragma unroll
                for (int r = 0; r < 4; ++r) {
                    cmb[(4 * 4 + r) * 64 + l] = acc[0][r];
                    cmb[(5 * 4 + r) * 64 + l] = acc[1][r];
                }
            }
            __syncthreads();                // cmb ready; img reads done
            if (w < 2) {                    // finisher: frag f = w
#pragma unroll
                for (int r = 0; r < 4; ++r) {
                    const float g0 = (w == 0) ? acc[0][r] : cmb[(0 * 4 + r) * 64 + l];
                    const float g1 = (w == 0) ? cmb[(1 * 4 + r) * 64 + l] : acc[1][r];
                    const float g2 = (w == 0) ? cmb[(2 * 4 + r) * 64 + l] : cmb[(3 * 4 + r) * 64 + l];
                    const float g3 = (w == 0) ? cmb[(4 * 4 + r) * 64 + l] : cmb[(5 * 4 + r) * 64 + l];
                    const float pi = fmaf(st[r], w0v[0], g0 + bv[0]);
                    const float pf = fmaf(st[r], w0v[1], g1 + bv[1]);
                    const float pg = fmaf(st[r], w0v[2], g2 + bv[2]);
                    const float po = fmaf(st[r], w0v[3], g3 + bv[3]);
                    const float ig = sigf(pi), fg = sigf(pf), gg = tanh_f(pg), og = sigf(po);
                    cst[r] = fmaf(fg, cst[r], ig * gg);
                    const float hn = og * tanh_f(cst[r]);
                    img[fi_f * 256 + (fq * 4 + r + 16 * (fr >> 2)) * 4 + (fr & 3)] = (f16)hn;
                }
            }
            __syncthreads();                // own 1 KB chunk complete in LDS
            if (w == 0) {
                u64* gd = (u64*)(gimg + (size_t)s * 4096);
                st_llc(gd + qm * 128 + l,      ((const u64*)img)[qm * 128 + l]);
                st_llc(gd + qm * 128 + 64 + l, ((const u64*)img)[qm * 128 + 64 + l]);
                asm volatile("s_waitcnt vmcnt(0)" ::: "memory");
                if (l == 0) st_flag(f0 + qm * 64, s + 1);
                if (s < NCLS - 1 && l < 7) {
                    const int p = l + (l >= qm);
                    while (ld_flag(f0 + p * 64) <= s) __builtin_amdgcn_s_sleep(1);
                }
            }
            if (s == NCLS - 1) break;
            __syncthreads();                // peers ready
            if (tid < 128) {
                const u64* gs = (const u64*)(gimg + (size_t)s * 4096);
                u64 tmp[7];
#pragma unroll
                for (int j = 0; j < 7; ++j) {
                    const int p = j + (j >= qm);
                    tmp[j] = ld_llc(gs + p * 128 + tid);
                }
#pragma unroll
                for (int j = 0; j < 7; ++j) {
                    const int p = j + (j >= qm);
                    ((u64*)img)[p * 128 + tid] = tmp[j];
                }
            }
            __syncthreads();                // img(s) complete
        }
    } else {
        // ================= LAYER 1 =================
        const float* bias = branch ? b1R : b1L;
        float bv[2][4];
#pragma unroll
        for (int f = 0; f < 2; ++f)
#pragma unroll
            for (int g4 = 0; g4 < 4; ++g4)
                bv[f][g4] = bias[g4 * 256 + (qm * 2 + f) * 16 + fr];
        float cst[2][4] = {{0.f,0.f,0.f,0.f},{0.f,0.f,0.f,0.f}};
        const f16* wstream = wih1 + ((size_t)branch << 18) + l * 8;
        const f16* gimg = h0img + (size_t)g * (NCLS * 4096);
        f16* gring = ring + (size_t)g * (4 * 4096);
        int* f0 = flags0 + g * 512;
        int* f1 = flags1 + g * 512;
        __syncthreads();
        if (w == 1 && l < 8) {              // wait for h0(0) (all 8 producers)
            while (ld_flag(f0 + l * 64) < 1) __builtin_amdgcn_s_sleep(2);
        }
        __syncthreads();
        f16x4 af0[16];
        {
            const u64* s2 = (const u64*)gimg + l;
#pragma unroll
            for (int kt = 0; kt < 16; ++kt)
                af0[kt] = __builtin_bit_cast(f16x4, ld_llc(s2 + kt * 64));
        }

        for (int t = 0; t < NCLS; ++t) {
            // stream Wih1 fragments (loop-invariant rows; L2-resident), issue early
            f16x8 wv[2][8];
#pragma unroll
            for (int f = 0; f < 2; ++f)
#pragma unroll
                for (int ktp = 0; ktp < 8; ++ktp)
                    wv[f][ktp] = *(const f16x8*)(wstream
                        + ((size_t)((w * 16 + qm * 2 + f) * 8 + ktp) << 9));
            f16x4 af1[16];
#pragma unroll
            for (int kt = 0; kt < 16; ++kt)
                af1[kt] = *(const f16x4*)(img + kt * 256 + l * 4);
            f32x4 acc[2];
#pragma unroll
            for (int f = 0; f < 2; ++f) {
                f32x4 a0 = {0.f,0.f,0.f,0.f}, a1 = {0.f,0.f,0.f,0.f};
#pragma unroll
                for (int ktp = 0; ktp < 8; ++ktp) {
                    const f16x8 v = *(const f16x8*)(wlds + (((w * 2 + f) * 8 + ktp) << 9) + l * 8);
                    a0 = __builtin_amdgcn_mfma_f32_16x16x16f16(af1[2 * ktp],     LO(v), a0, 0, 0, 0);
                    a1 = __builtin_amdgcn_mfma_f32_16x16x16f16(af1[2 * ktp + 1], HI(v), a1, 0, 0, 0);
                }
#pragma unroll
                for (int ktp = 0; ktp < 8; ++ktp) {
                    a0 = __builtin_amdgcn_mfma_f32_16x16x16f16(af0[2 * ktp],     LO(wv[f][ktp]), a0, 0, 0, 0);
                    a1 = __builtin_amdgcn_mfma_f32_16x16x16f16(af0[2 * ktp + 1], HI(wv[f][ktp]), a1, 0, 0, 0);
                }
                acc[f] = a0 + a1;
            }
            if (w > 0) {                    // publish: e = (w-1)*2+f
#pragma unroll
                for (int f = 0; f < 2; ++f)
#pragma unroll
                    for (int r = 0; r < 4; ++r)
                        cmb[(((w - 1) * 2 + f) * 4 + r) * 64 + l] = acc[f][r];
            }
            __syncthreads();                // cmb ready; img reads done
            if (w == 0) {                   // finisher: both frags
#pragma unroll
                for (int f = 0; f < 2; ++f) {
#pragma unroll
                    for (int r = 0; r < 4; ++r) {
                        const float g0 = acc[f][r];
                        const float g1 = cmb[((0 * 2 + f) * 4 + r) * 64 + l];
                        const float g2 = cmb[((1 * 2 + f) * 4 + r) * 64 + l];
                        const float g3 = cmb[((2 * 2 + f) * 4 + r) * 64 + l];
                        const float pi = g0 + bv[f][0];
                        const float pf = g1 + bv[f][1];
                        const float pg = g2 + bv[f][2];
                        const float po = g3 + bv[f][3];
                        const float ig = sigf(pi), fg = sigf(pf), gg = tanh_f(pg), og = sigf(po);
                        cst[f][r] = fmaf(fg, cst[f][r], ig * gg);
                        const float hn = og * tanh_f(cst[f][r]);
                        if (t == NCLS - 1)
                            h1out[((size_t)(branch * NBATCH + tb * 16 + fq * 4 + r)) * NHID
                                  + (qm * 2 + f) * 16 + fr] = hn;
                        else
                            img[(qm * 2 + f) * 256 + (fq * 4 + r + 16 * (fr >> 2)) * 4 + (fr & 3)] = (f16)hn;
                    }
                }
            }
            if (t == NCLS - 1) break;
            f16* slot = gring + (size_t)(t & 3) * 4096;
            if (w == 0) {                   // push own chunk (own-wave writes)
                asm volatile("s_waitcnt lgkmcnt(0)" ::: "memory");
                u64* gd = (u64*)slot;
                st_llc(gd + qm * 128 + l,      ((const u64*)img)[qm * 128 + l]);
                st_llc(gd + qm * 128 + 64 + l, ((const u64*)img)[qm * 128 + 64 + l]);
                asm volatile("s_waitcnt vmcnt(0)" ::: "memory");
                if (l == 0) st_flag(f1 + qm * 64, t + 1);
                if (l < 7) {
                    const int p = l + (l >= qm);
                    while (ld_flag(f1 + p * 64) <= t) __builtin_amdgcn_s_sleep(1);
                }
            }
            if (w == 1 && l < 8) {          // h0(t+1) ready? (flags0 monotonic)
                while (ld_flag(f0 + l * 64) < t + 2) __builtin_amdgcn_s_sleep(1);
            }
            __syncthreads();                // peers + h0(t+1) ready
            {                               // prefetch h0(t+1) frags (all waves)
                const u64* s2 = (const u64*)(gimg + (size_t)(t + 1) * 4096) + l;
#pragma unroll
                for (int kt = 0; kt < 16; ++kt)
                    af0[kt] = __builtin_bit_cast(f16x4, ld_llc(s2 + kt * 64));
            }
            if (tid < 128) {                // gather peers' h1(t)
                const u64* gs = (const u64*)slot;
                u64 tmp[7];
#pragma unroll
                for (int j = 0; j < 7; ++j) {
                    const int p = j + (j >= qm);
                    tmp[j] = ld_llc(gs + p * 128 + tid);
                }
#pragma unroll
                for (int j = 0; j < 7; ++j) {
                    const int p = j + (j >= qm);
                    ((u64*)img)[p * 128 + tid] = tmp[j];
                }
            }
            __syncthreads();                // img(t) complete
        }
    }
}

// ---------------- K4: MLP head (2H -> 200 -> 128), f32 ------------------------
__global__ __launch_bounds__(256) void k_mlp(
    const float* __restrict__ h1all,   // [2][256][256]
    const float* __restrict__ W1, const float* __restrict__ b1,
    const float* __restrict__ W2, const float* __restrict__ b2,
    float* __restrict__ out)
{
    __shared__ float hrow[512];
    __shared__ float hid[200];
    const int b = blockIdx.x, tid = threadIdx.x;
    hrow[tid]       = h1all[(size_t)b * NHID + tid];
    hrow[256 + tid] = h1all[(size_t)(NBATCH + b) * NHID + tid];
    __syncthreads();
    if (tid < 200) {
        float a = b1[tid];
        const float* wr = W1 + (size_t)tid * 512;
        for (int k = 0; k < 512; ++k) a = fmaf(wr[k], hrow[k], a);
        hid[tid] = fmaxf(a, 0.f);
    }
    __syncthreads();
    if (tid < 128) {
        float a = b2[tid];
        const float* wr = W2 + (size_t)tid * 200;
        for (int j = 0; j < 200; ++j) a = fmaf(wr[j], hid[j], a);
        out[(size_t)b * 128 + tid] = a;
    }
}

// ---------------- launch ------------------------------------------------------
extern "C" void kernel_launch(void* const* d_in, const int* in_sizes, int n_in,
                              void* d_out, int out_size, void* d_ws, size_t ws_size,
                              hipStream_t stream)
{
    (void)in_sizes; (void)n_in; (void)out_size; (void)ws_size;
    const int*   ln    = (const int*)d_in[0];
    const int*   rn    = (const int*)d_in[2];
    const float* tlW   = (const float*)d_in[4];
    const float* tlU   = (const float*)d_in[5];
    const float* tlb   = (const float*)d_in[6];
    const float* trW   = (const float*)d_in[7];
    const float* trU   = (const float*)d_in[8];
    const float* trb   = (const float*)d_in[9];
    const float* wih0L = (const float*)d_in[10];
    const float* b0L   = (const float*)d_in[12];
    const float* b1L   = (const float*)d_in[15];
    const float* wih0R = (const float*)d_in[16];
    const float* b0R   = (const float*)d_in[18];
    const float* b1R   = (const float*)d_in[21];
    const float* mW1   = (const float*)d_in[22];
    const float* mb1   = (const float*)d_in[23];
    const float* mW2   = (const float*)d_in[24];
    const float* mb2   = (const float*)d_in[25];

    // workspace layout (bytes)
    char* ws = (char*)d_ws;
    f16*   w16    = (f16*)ws;                        // 3 MB swizzled weights
    float* states = (float*)(ws + 3145728);          // 256 KB
    float* h1out  = (float*)(ws + 3407872);          // 512 KB
    int*   flags  = (int*)(ws + 3932160);            // 128 KB (2 x 32 x 8 x 64 ints)
    f16*   ring   = (f16*)(ws + 4063232);            // 1 MB (32 x 4 x 4096 f16)
    f16*   h0img  = (f16*)(ws + 5111808);            // 32 MB (32 x 128 x 4096 f16)

    f16* whh0 = w16;
    f16* whh1 = w16 + 2 * 262144;
    f16* wih1 = w16 + 4 * 262144;
    int* flags0 = flags;
    int* flags1 = flags + 16384;

    (void)hipFuncSetAttribute(reinterpret_cast<const void*>(k_rec),
                              hipFuncAttributeMaxDynamicSharedMemorySize, 79872);

    P6 p { (const float*)d_in[11], (const float*)d_in[17],   // nl_Whh0, nr_Whh0
           (const float*)d_in[14], (const float*)d_in[20],   // nl_Whh1, nr_Whh1
           (const float*)d_in[13], (const float*)d_in[19] }; // nl_Wih1, nr_Wih1
    k_pre<<<770, 256, 0, stream>>>(ln, rn, tlW, tlU, tlb, trW, trU, trb,
                                   states, p, w16, flags);
    k_rec<<<512, 256, 79872, stream>>>(states, whh0, whh1, wih1, wih0L, wih0R,
                                       b0L, b0R, b1L, b1R, h0img, ring,
                                       flags0, flags1, h1out);
    k_mlp<<<256, 256, 0, stream>>>(h1out, mW1, mb1, mW2, mb2, (float*)d_out);
}

// Round 16
// 601.993 us; speedup vs baseline: 1.3842x; 1.0633x over previous
//
#include <hip/hip_runtime.h>

// VoiceModel: 2 branches x { scalar-LSTM(1->1,L2) over T=512 per (b,class),
// then LSTM(1->256,L2) over 128 class-steps }, concat -> MLP(512->200->128).
// Round 16: round-15 + wave-role overlap in k_rec: peer-flag polls run on idle
// waves CONCURRENTLY with wave-0's push+flag (L0: w2 polls; L1: w2 polls f1,
// w3 polls f0), and L1's finisher is split across waves 0/1. Protocol bytes
// identical to proven round-9/13 (relaxed-sc1 + vmcnt(0)-ordered flags).

typedef _Float16 f16;
typedef __attribute__((ext_vector_type(4))) _Float16 f16x4;
typedef __attribute__((ext_vector_type(8))) _Float16 f16x8;
typedef __attribute__((ext_vector_type(4))) float f32x4;
typedef unsigned long long u64;

#define NBATCH 256
#define NTIME  512
#define NCLS   128
#define NHID   256

__device__ __forceinline__ float sigf(float x) {
    return __builtin_amdgcn_rcpf(1.0f + __expf(-x));
}
__device__ __forceinline__ float tanh_f(float x) {
    return fmaf(2.0f, __builtin_amdgcn_rcpf(1.0f + __expf(-2.0f * x)), -1.0f);
}
__device__ __forceinline__ f16x4 LO(f16x8 v) { f16x4 r; r[0]=v[0]; r[1]=v[1]; r[2]=v[2]; r[3]=v[3]; return r; }
__device__ __forceinline__ f16x4 HI(f16x8 v) { f16x4 r; r[0]=v[4]; r[1]=v[5]; r[2]=v[6]; r[3]=v[7]; return r; }

// LLC-coherent (sc1) relaxed agent atomics (proven round 9).
__device__ __forceinline__ u64 ld_llc(const u64* p) {
    return __hip_atomic_load(p, __ATOMIC_RELAXED, __HIP_MEMORY_SCOPE_AGENT);
}
__device__ __forceinline__ void st_llc(u64* p, u64 v) {
    __hip_atomic_store(p, v, __ATOMIC_RELAXED, __HIP_MEMORY_SCOPE_AGENT);
}
__device__ __forceinline__ int ld_flag(const int* p) {
    return __hip_atomic_load(p, __ATOMIC_RELAXED, __HIP_MEMORY_SCOPE_AGENT);
}
__device__ __forceinline__ void st_flag(int* p, int v) {
    __hip_atomic_store(p, v, __ATOMIC_RELAXED, __HIP_MEMORY_SCOPE_AGENT);
}

struct P6 {
    const float* s0; const float* s1; const float* s2;
    const float* s3; const float* s4; const float* s5;
};

// ---------------- K_PRE: fused {scalar-LSTM | weight cvt+swizzle | flag zero} --
// grid 770 x 256 thr (round-15, measured ~90us total under scalar phase).
__global__ __launch_bounds__(256) void k_pre(
    const int* __restrict__ ln, const int* __restrict__ rn,
    const float* __restrict__ tlW, const float* __restrict__ tlU, const float* __restrict__ tlb,
    const float* __restrict__ trW, const float* __restrict__ trU, const float* __restrict__ trb,
    float* __restrict__ states,
    P6 p, f16* __restrict__ wdst,
    int* __restrict__ flags)
{
    const int bid = blockIdx.x;
    const int tid = threadIdx.x;
    if (bid >= 768) {                      // ---- flag zero ----
        int* f = flags + (bid - 768) * 16384;
        for (int i = tid; i < 16384; i += 256) f[i] = 0;
        return;
    }
    if (bid >= 256) {                      // ---- weight cvt ----
        const int base = (bid - 256) * 3072;
#pragma unroll
        for (int k = 0; k < 12; ++k) {
            const int i = base + k * 256 + tid;
            const int seg = i >> 18, d = i & 262143;
            const float* s = seg == 0 ? p.s0 : seg == 1 ? p.s1 : seg == 2 ? p.s2
                           : seg == 3 ? p.s3 : seg == 4 ? p.s4 : p.s5;
            const int e  = d & 7;
            const int fr = (d >> 3) & 15;
            const int fq = (d >> 7) & 3;
            const int ktp = (d >> 9) & 7;
            const int fi = (d >> 12) & 15;
            const int g  = (d >> 16) & 3;
            const int row = g * 256 + fi * 16 + fr;
            const int col = ktp * 32 + (e >> 2) * 16 + fq * 4 + (e & 3);
            wdst[i] = (f16)s[row * 256 + col];
        }
        return;
    }
    // ---- scalar LSTM: 2 chains per block, L0(t) || L1(t-1) pipelined ----
    __shared__ int tok[2][NTIME];
    const int half = tid >> 7, n = tid & 127;
    const int pair = bid * 2 + half;
    const int branch = pair >> 8;
    const int b = pair & 255;
    const int* tp = (branch ? rn : ln) + (size_t)b * (4 * NTIME);  // voice 0
    for (int i = n; i < NTIME; i += 128) tok[half][i] = tp[i];
    __syncthreads();
    const float* W  = branch ? trW : tlW;
    const float* U  = branch ? trU : tlU;
    const float* Bb = branch ? trb : tlb;
    const float u00 = U[0], u01 = U[1], u02 = U[2], u03 = U[3];
    const float f00 = Bb[0], f01 = Bb[1], f02 = Bb[2], f03 = Bb[3];
    const float o00 = f00 + W[0], o01 = f01 + W[1], o02 = f02 + W[2], o03 = f03 + W[3];
    const float w10 = W[4], w11 = W[5], w12 = W[6], w13 = W[7];
    const float u10 = U[4], u11 = U[5], u12 = U[6], u13 = U[7];
    const float b10 = Bb[4], b11 = Bb[5], b12 = Bb[6], b13 = Bb[7];
    float h0 = 0.f, c0 = 0.f, h1 = 0.f, c1 = 0.f;
    {   // L0 step 0
        const bool x = (tok[half][0] == n);
        float pi = fmaf(u00, h0, x ? o00 : f00);
        float pf = fmaf(u01, h0, x ? o01 : f01);
        float pg = fmaf(u02, h0, x ? o02 : f02);
        float po = fmaf(u03, h0, x ? o03 : f03);
        const float ig = sigf(pi), fg = sigf(pf), gg = tanh_f(pg), og = sigf(po);
        c0 = fmaf(fg, c0, ig * gg);
        h0 = og * tanh_f(c0);
    }
    for (int t = 1; t < NTIME; ++t) {
        const bool x = (tok[half][t] == n);
        float api = fmaf(u00, h0, x ? o00 : f00);
        float apf = fmaf(u01, h0, x ? o01 : f01);
        float apg = fmaf(u02, h0, x ? o02 : f02);
        float apo = fmaf(u03, h0, x ? o03 : f03);
        float bpi = fmaf(w10, h0, fmaf(u10, h1, b10));
        float bpf = fmaf(w11, h0, fmaf(u11, h1, b11));
        float bpg = fmaf(w12, h0, fmaf(u12, h1, b12));
        float bpo = fmaf(w13, h0, fmaf(u13, h1, b13));
        const float aig = sigf(api), afg = sigf(apf), agg = tanh_f(apg), aog = sigf(apo);
        const float big = sigf(bpi), bfg = sigf(bpf), bgg = tanh_f(bpg), bog = sigf(bpo);
        c0 = fmaf(afg, c0, aig * agg);
        c1 = fmaf(bfg, c1, big * bgg);
        h0 = aog * tanh_f(c0);
        h1 = bog * tanh_f(c1);
    }
    {   // final L1 step
        float pi = fmaf(w10, h0, fmaf(u10, h1, b10));
        float pf = fmaf(w11, h0, fmaf(u11, h1, b11));
        float pg = fmaf(w12, h0, fmaf(u12, h1, b12));
        float po = fmaf(w13, h0, fmaf(u13, h1, b13));
        const float ig = sigf(pi), fg = sigf(pf), gg = tanh_f(pg), og = sigf(po);
        c1 = fmaf(fg, c1, ig * gg);
        h1 = og * tanh_f(c1);
    }
    states[((size_t)(branch * NBATCH + b)) * NCLS + n] = h1;
}

// ---------------- K2: pipelined L0+L1 recurrence (512 blocks) ----------------
// blocks 0-255: layer 0; blocks 256-511: layer 1 (lag-1 on h0img via flags0).
// Wave roles per step (both layers): waves 0/1 finish; wave 0 pushes+flags;
// wave 2 polls peer flags CONCURRENTLY with the push; (L1) wave 3 polls f0.
__global__ __launch_bounds__(256, 2) void k_rec(
    const float* __restrict__ states,
    const f16* __restrict__ whh0, const f16* __restrict__ whh1,
    const f16* __restrict__ wih1,
    const float* __restrict__ wih0L, const float* __restrict__ wih0R,
    const float* __restrict__ b0L, const float* __restrict__ b0R,
    const float* __restrict__ b1L, const float* __restrict__ b1R,
    f16* __restrict__ h0img,               // [32 group][128 s][4096]
    f16* __restrict__ ring,                // [32 group][4 slot][4096]
    int* __restrict__ flags0,              // [32 group][8] stride 64 ints
    int* __restrict__ flags1,              // [32 group][8] stride 64 ints
    float* __restrict__ h1out)             // [2][256][256] f32
{
    extern __shared__ char smem[];
    f16*   wlds = (f16*)smem;                    // 65536 B weight slice
    f16*   img  = (f16*)(smem + 65536);          // 8192 B h image
    float* cmb  = (float*)(smem + 73728);        // 6144 B  (total 79872)

    const int bid = blockIdx.x;
    const bool isL1 = bid >= 256;
    const int sub = isL1 ? (bid - 256) : bid;
    const int qm = sub >> 5, g = sub & 31;
    const int branch = g >> 4, tb = g & 15;
    const int tid = threadIdx.x;
    const int w = tid >> 6, l = tid & 63, fr = l & 15, fq = l >> 4;

    {   // stage the recurrent weight slice (Whh0 or Whh1): 64 rows x 512 f16
        const f16* base = (isL1 ? whh1 : whh0) + ((size_t)branch << 18);
        for (int c = tid; c < 4096; c += 256) {
            const int rl = c >> 6, coli = c & 63;
            const int gg = rl >> 4, ff = (rl >> 3) & 1, ktp = rl & 7;
            *(uint4*)(wlds + rl * 512 + coli * 8) =
                *(const uint4*)(base + ((size_t)((gg * 16 + qm * 2 + ff) * 8 + ktp) << 9) + coli * 8);
        }
    }
    ((uint4*)img)[tid] = (uint4){0u, 0u, 0u, 0u};
    ((uint4*)img)[tid + 256] = (uint4){0u, 0u, 0u, 0u};

    if (!isL1) {
        // ================= LAYER 0 =================
        const float* bias = branch ? b0R : b0L;
        const float* w0p  = branch ? wih0R : wih0L;
        const int fi_f = qm * 2 + (w < 2 ? w : 0);
        float bv[4], w0v[4];
#pragma unroll
        for (int g4 = 0; g4 < 4; ++g4) {
            bv[g4]  = bias[g4 * 256 + fi_f * 16 + fr];
            w0v[g4] = w0p[g4 * 256 + fi_f * 16 + fr];
        }
        float cst[4] = {0.f, 0.f, 0.f, 0.f};
        f16* gimg = h0img + (size_t)g * (NCLS * 4096);
        int* f0 = flags0 + g * 512;
        __syncthreads();

        for (int s = 0; s < NCLS; ++s) {
            float st[4];
            if (w < 2) {
#pragma unroll
                for (int r = 0; r < 4; ++r)
                    st[r] = states[((size_t)(branch * NBATCH + tb * 16 + fq * 4 + r)) * NCLS + s];
            }
            f16x4 af[16];
#pragma unroll
            for (int kt = 0; kt < 16; ++kt)
                af[kt] = *(const f16x4*)(img + kt * 256 + l * 4);
            f32x4 acc[2];
#pragma unroll
            for (int f = 0; f < 2; ++f) {
                f32x4 a0 = {0.f,0.f,0.f,0.f}, a1 = {0.f,0.f,0.f,0.f};
#pragma unroll
                for (int ktp = 0; ktp < 8; ++ktp) {
                    const f16x8 v = *(const f16x8*)(wlds + (((w * 2 + f) * 8 + ktp) << 9) + l * 8);
                    a0 = __builtin_amdgcn_mfma_f32_16x16x16f16(af[2 * ktp],     LO(v), a0, 0, 0, 0);
                    a1 = __builtin_amdgcn_mfma_f32_16x16x16f16(af[2 * ktp + 1], HI(v), a1, 0, 0, 0);
                }
                acc[f] = a0 + a1;
            }
            // publish: e0=(w0,f1) e1=(w1,f0) e2=(w2,f0) e3=(w2,f1) e4=(w3,f0) e5=(w3,f1)
            if (w == 0) {
#pragma unroll
                for (int r = 0; r < 4; ++r) cmb[(0 * 4 + r) * 64 + l] = acc[1][r];
            } else if (w == 1) {
#pragma unroll
                for (int r = 0; r < 4; ++r) cmb[(1 * 4 + r) * 64 + l] = acc[0][r];
            } else if (w == 2) {
#pragma unroll
                for (int r = 0; r < 4; ++r) {
                    cmb[(2 * 4 + r) * 64 + l] = acc[0][r];
                    cmb[(3 * 4 + r) * 64 + l] = acc[1][r];
                }
            } else {
#pragma unroll
                for (int r = 0; r < 4; ++r) {
                    cmb[(4 * 4 + r) * 64 + l] = acc[0][r];
                    cmb[(5 * 4 + r) * 64 + l] = acc[1][r];
                }
            }
            __syncthreads();                // cmb ready; img reads done
            if (w < 2) {                    // finisher: frag f = w
#pragma unroll
                for (int r = 0; r < 4; ++r) {
                    const float g0 = (w == 0) ? acc[0][r] : cmb[(0 * 4 + r) * 64 + l];
                    const float g1 = (w == 0) ? cmb[(1 * 4 + r) * 64 + l] : acc[1][r];
                    const float g2 = (w == 0) ? cmb[(2 * 4 + r) * 64 + l] : cmb[(3 * 4 + r) * 64 + l];
                    const float g3 = (w == 0) ? cmb[(4 * 4 + r) * 64 + l] : cmb[(5 * 4 + r) * 64 + l];
                    const float pi = fmaf(st[r], w0v[0], g0 + bv[0]);
                    const float pf = fmaf(st[r], w0v[1], g1 + bv[1]);
                    const float pg = fmaf(st[r], w0v[2], g2 + bv[2]);
                    const float po = fmaf(st[r], w0v[3], g3 + bv[3]);
                    const float ig = sigf(pi), fg = sigf(pf), gg = tanh_f(pg), og = sigf(po);
                    cst[r] = fmaf(fg, cst[r], ig * gg);
                    const float hn = og * tanh_f(cst[r]);
                    img[fi_f * 256 + (fq * 4 + r + 16 * (fr >> 2)) * 4 + (fr & 3)] = (f16)hn;
                }
            }
            __syncthreads();                // own 1 KB chunk complete in LDS
            if (w == 0) {                   // push + flag (poll runs on wave 2)
                u64* gd = (u64*)(gimg + (size_t)s * 4096);
                st_llc(gd + qm * 128 + l,      ((const u64*)img)[qm * 128 + l]);
                st_llc(gd + qm * 128 + 64 + l, ((const u64*)img)[qm * 128 + 64 + l]);
                asm volatile("s_waitcnt vmcnt(0)" ::: "memory");
                if (l == 0) st_flag(f0 + qm * 64, s + 1);
            } else if (w == 2 && s < NCLS - 1 && l < 7) {   // concurrent peer poll
                const int p = l + (l >= qm);
                while (ld_flag(f0 + p * 64) <= s) __builtin_amdgcn_s_sleep(1);
            }
            if (s == NCLS - 1) break;
            __syncthreads();                // peers ready (wave-2 poll done)
            if (tid < 128) {
                const u64* gs = (const u64*)(gimg + (size_t)s * 4096);
                u64 tmp[7];
#pragma unroll
                for (int j = 0; j < 7; ++j) {
                    const int p = j + (j >= qm);
                    tmp[j] = ld_llc(gs + p * 128 + tid);
                }
#pragma unroll
                for (int j = 0; j < 7; ++j) {
                    const int p = j + (j >= qm);
                    ((u64*)img)[p * 128 + tid] = tmp[j];
                }
            }
            __syncthreads();                // img(s) complete
        }
    } else {
        // ================= LAYER 1 =================
        const float* bias = branch ? b1R : b1L;
        const int fi_f = qm * 2 + (w < 2 ? w : 0);   // finisher frag (w0->0, w1->1)
        float bv[4];
#pragma unroll
        for (int g4 = 0; g4 < 4; ++g4) bv[g4] = bias[g4 * 256 + fi_f * 16 + fr];
        float cst[4] = {0.f, 0.f, 0.f, 0.f};
        const f16* wstream = wih1 + ((size_t)branch << 18) + l * 8;
        const f16* gimg = h0img + (size_t)g * (NCLS * 4096);
        f16* gring = ring + (size_t)g * (4 * 4096);
        int* f0 = flags0 + g * 512;
        int* f1 = flags1 + g * 512;
        __syncthreads();
        if (w == 3 && l < 8) {              // wait for h0(0) (all 8 producers)
            while (ld_flag(f0 + l * 64) < 1) __builtin_amdgcn_s_sleep(2);
        }
        __syncthreads();
        f16x4 af0[16];
        {
            const u64* s2 = (const u64*)gimg + l;
#pragma unroll
            for (int kt = 0; kt < 16; ++kt)
                af0[kt] = __builtin_bit_cast(f16x4, ld_llc(s2 + kt * 64));
        }

        for (int t = 0; t < NCLS; ++t) {
            // stream Wih1 fragments (loop-invariant rows; L2-resident), issue early
            f16x8 wv[2][8];
#pragma unroll
            for (int f = 0; f < 2; ++f)
#pragma unroll
                for (int ktp = 0; ktp < 8; ++ktp)
                    wv[f][ktp] = *(const f16x8*)(wstream
                        + ((size_t)((w * 16 + qm * 2 + f) * 8 + ktp) << 9));
            f16x4 af1[16];
#pragma unroll
            for (int kt = 0; kt < 16; ++kt)
                af1[kt] = *(const f16x4*)(img + kt * 256 + l * 4);
            f32x4 acc[2];
#pragma unroll
            for (int f = 0; f < 2; ++f) {
                f32x4 a0 = {0.f,0.f,0.f,0.f}, a1 = {0.f,0.f,0.f,0.f};
#pragma unroll
                for (int ktp = 0; ktp < 8; ++ktp) {
                    const f16x8 v = *(const f16x8*)(wlds + (((w * 2 + f) * 8 + ktp) << 9) + l * 8);
                    a0 = __builtin_amdgcn_mfma_f32_16x16x16f16(af1[2 * ktp],     LO(v), a0, 0, 0, 0);
                    a1 = __builtin_amdgcn_mfma_f32_16x16x16f16(af1[2 * ktp + 1], HI(v), a1, 0, 0, 0);
                }
#pragma unroll
                for (int ktp = 0; ktp < 8; ++ktp) {
                    a0 = __builtin_amdgcn_mfma_f32_16x16x16f16(af0[2 * ktp],     LO(wv[f][ktp]), a0, 0, 0, 0);
                    a1 = __builtin_amdgcn_mfma_f32_16x16x16f16(af0[2 * ktp + 1], HI(wv[f][ktp]), a1, 0, 0, 0);
                }
                acc[f] = a0 + a1;
            }
            // publish for split finishers (w0->frag0, w1->frag1):
            // slots: 0=(w1,f0) 1=(w2,f0) 2=(w3,f0) 3=(w0,f1) 4=(w2,f1) 5=(w3,f1)
            if (w == 0) {
#pragma unroll
                for (int r = 0; r < 4; ++r) cmb[(3 * 4 + r) * 64 + l] = acc[1][r];
            } else if (w == 1) {
#pragma unroll
                for (int r = 0; r < 4; ++r) cmb[(0 * 4 + r) * 64 + l] = acc[0][r];
            } else if (w == 2) {
#pragma unroll
                for (int r = 0; r < 4; ++r) {
                    cmb[(1 * 4 + r) * 64 + l] = acc[0][r];
                    cmb[(4 * 4 + r) * 64 + l] = acc[1][r];
                }
            } else {
#pragma unroll
                for (int r = 0; r < 4; ++r) {
                    cmb[(2 * 4 + r) * 64 + l] = acc[0][r];
                    cmb[(5 * 4 + r) * 64 + l] = acc[1][r];
                }
            }
            __syncthreads();                // cmb ready; img reads done
            if (w < 2) {                    // finisher: frag f = w
#pragma unroll
                for (int r = 0; r < 4; ++r) {
                    const float g0 = (w == 0) ? acc[0][r] : cmb[(3 * 4 + r) * 64 + l];
                    const float g1 = (w == 0) ? cmb[(0 * 4 + r) * 64 + l] : acc[1][r];
                    const float g2 = (w == 0) ? cmb[(1 * 4 + r) * 64 + l] : cmb[(4 * 4 + r) * 64 + l];
                    const float g3 = (w == 0) ? cmb[(2 * 4 + r) * 64 + l] : cmb[(5 * 4 + r) * 64 + l];
                    const float pi = g0 + bv[0];
                    const float pf = g1 + bv[1];
                    const float pg = g2 + bv[2];
                    const float po = g3 + bv[3];
                    const float ig = sigf(pi), fg = sigf(pf), gg = tanh_f(pg), og = sigf(po);
                    cst[r] = fmaf(fg, cst[r], ig * gg);
                    const float hn = og * tanh_f(cst[r]);
                    if (t == NCLS - 1)
                        h1out[((size_t)(branch * NBATCH + tb * 16 + fq * 4 + r)) * NHID
                              + fi_f * 16 + fr] = hn;
                    else
                        img[fi_f * 256 + (fq * 4 + r + 16 * (fr >> 2)) * 4 + (fr & 3)] = (f16)hn;
                }
            }
            if (t == NCLS - 1) break;
            __syncthreads();                // own 1 KB chunk complete in LDS
            f16* slot = gring + (size_t)(t & 3) * 4096;
            if (w == 0) {                   // push + flag (polls run on waves 2/3)
                u64* gd = (u64*)slot;
                st_llc(gd + qm * 128 + l,      ((const u64*)img)[qm * 128 + l]);
                st_llc(gd + qm * 128 + 64 + l, ((const u64*)img)[qm * 128 + 64 + l]);
                asm volatile("s_waitcnt vmcnt(0)" ::: "memory");
                if (l == 0) st_flag(f1 + qm * 64, t + 1);
            } else if (w == 2 && l < 7) {   // concurrent peer h1 poll
                const int p = l + (l >= qm);
                while (ld_flag(f1 + p * 64) <= t) __builtin_amdgcn_s_sleep(1);
            } else if (w == 3 && l < 8) {   // concurrent h0(t+1) poll (monotonic)
                while (ld_flag(f0 + l * 64) < t + 2) __builtin_amdgcn_s_sleep(1);
            }
            __syncthreads();                // peers + h0(t+1) ready
            {                               // prefetch h0(t+1) frags (all waves)
                const u64* s2 = (const u64*)(gimg + (size_t)(t + 1) * 4096) + l;
#pragma unroll
                for (int kt = 0; kt < 16; ++kt)
                    af0[kt] = __builtin_bit_cast(f16x4, ld_llc(s2 + kt * 64));
            }
            if (tid < 128) {                // gather peers' h1(t)
                const u64* gs = (const u64*)slot;
                u64 tmp[7];
#pragma unroll
                for (int j = 0; j < 7; ++j) {
                    const int p = j + (j >= qm);
                    tmp[j] = ld_llc(gs + p * 128 + tid);
                }
#pragma unroll
                for (int j = 0; j < 7; ++j) {
                    const int p = j + (j >= qm);
                    ((u64*)img)[p * 128 + tid] = tmp[j];
                }
            }
            __syncthreads();                // img(t) complete
        }
    }
}

// ---------------- K4: MLP head (2H -> 200 -> 128), f32 ------------------------
__global__ __launch_bounds__(256) void k_mlp(
    const float* __restrict__ h1all,   // [2][256][256]
    const float* __restrict__ W1, const float* __restrict__ b1,
    const float* __restrict__ W2, const float* __restrict__ b2,
    float* __restrict__ out)
{
    __shared__ float hrow[512];
    __shared__ float hid[200];
    const int b = blockIdx.x, tid = threadIdx.x;
    hrow[tid]       = h1all[(size_t)b * NHID + tid];
    hrow[256 + tid] = h1all[(size_t)(NBATCH + b) * NHID + tid];
    __syncthreads();
    if (tid < 200) {
        float a = b1[tid];
        const float* wr = W1 + (size_t)tid * 512;
        for (int k = 0; k < 512; ++k) a = fmaf(wr[k], hrow[k], a);
        hid[tid] = fmaxf(a, 0.f);
    }
    __syncthreads();
    if (tid < 128) {
        float a = b2[tid];
        const float* wr = W2 + (size_t)tid * 200;
        for (int j = 0; j < 200; ++j) a = fmaf(wr[j], hid[j], a);
        out[(size_t)b * 128 + tid] = a;
    }
}

// ---------------- launch ------------------------------------------------------
extern "C" void kernel_launch(void* const* d_in, const int* in_sizes, int n_in,
                              void* d_out, int out_size, void* d_ws, size_t ws_size,
                              hipStream_t stream)
{
    (void)in_sizes; (void)n_in; (void)out_size; (void)ws_size;
    const int*   ln    = (const int*)d_in[0];
    const int*   rn    = (const int*)d_in[2];
    const float* tlW   = (const float*)d_in[4];
    const float* tlU   = (const float*)d_in[5];
    const float* tlb   = (const float*)d_in[6];
    const float* trW   = (const float*)d_in[7];
    const float* trU   = (const float*)d_in[8];
    const float* trb   = (const float*)d_in[9];
    const float* wih0L = (const float*)d_in[10];
    const float* b0L   = (const float*)d_in[12];
    const float* b1L   = (const float*)d_in[15];
    const float* wih0R = (const float*)d_in[16];
    const float* b0R   = (const float*)d_in[18];
    const float* b1R   = (const float*)d_in[21];
    const float* mW1   = (const float*)d_in[22];
    const float* mb1   = (const float*)d_in[23];
    const float* mW2   = (const float*)d_in[24];
    const float* mb2   = (const float*)d_in[25];

    // workspace layout (bytes)
    char* ws = (char*)d_ws;
    f16*   w16    = (f16*)ws;                        // 3 MB swizzled weights
    float* states = (float*)(ws + 3145728);          // 256 KB
    float* h1out  = (float*)(ws + 3407872);          // 512 KB
    int*   flags  = (int*)(ws + 3932160);            // 128 KB (2 x 32 x 8 x 64 ints)
    f16*   ring   = (f16*)(ws + 4063232);            // 1 MB (32 x 4 x 4096 f16)
    f16*   h0img  = (f16*)(ws + 5111808);            // 32 MB (32 x 128 x 4096 f16)

    f16* whh0 = w16;
    f16* whh1 = w16 + 2 * 262144;
    f16* wih1 = w16 + 4 * 262144;
    int* flags0 = flags;
    int* flags1 = flags + 16384;

    (void)hipFuncSetAttribute(reinterpret_cast<const void*>(k_rec),
                              hipFuncAttributeMaxDynamicSharedMemorySize, 79872);

    P6 p { (const float*)d_in[11], (const float*)d_in[17],   // nl_Whh0, nr_Whh0
           (const float*)d_in[14], (const float*)d_in[20],   // nl_Whh1, nr_Whh1
           (const float*)d_in[13], (const float*)d_in[19] }; // nl_Wih1, nr_Wih1
    k_pre<<<770, 256, 0, stream>>>(ln, rn, tlW, tlU, tlb, trW, trU, trb,
                                   states, p, w16, flags);
    k_rec<<<512, 256, 79872, stream>>>(states, whh0, whh1, wih1, wih0L, wih0R,
                                       b0L, b0R, b1L, b1R, h0img, ring,
                                       flags0, flags1, h1out);
    k_mlp<<<256, 256, 0, stream>>>(h1out, mW1, mb1, mW2, mb2, (float*)d_out);
}

// Round 17
// 589.873 us; speedup vs baseline: 1.4127x; 1.0205x over previous
//
#include <hip/hip_runtime.h>

// VoiceModel: 2 branches x { scalar-LSTM(1->1,L2) over T=512 per (b,class),
// then LSTM(1->256,L2) over 128 class-steps }, concat -> MLP(512->200->128).
// Round 17: round-16 + (a) gather phase removed — af fragments loaded DIRECTLY
// from the LLC image at step top (slot s-1; zeros at s=0), 3 barriers/step;
// (b) dual-outstanding flag polls (no s_sleep). Protocol otherwise identical
// to proven round-9/13/16 (relaxed-sc1 + vmcnt(0)-ordered monotonic flags).

typedef _Float16 f16;
typedef __attribute__((ext_vector_type(4))) _Float16 f16x4;
typedef __attribute__((ext_vector_type(8))) _Float16 f16x8;
typedef __attribute__((ext_vector_type(4))) float f32x4;
typedef unsigned long long u64;

#define NBATCH 256
#define NTIME  512
#define NCLS   128
#define NHID   256

__device__ __forceinline__ float sigf(float x) {
    return __builtin_amdgcn_rcpf(1.0f + __expf(-x));
}
__device__ __forceinline__ float tanh_f(float x) {
    return fmaf(2.0f, __builtin_amdgcn_rcpf(1.0f + __expf(-2.0f * x)), -1.0f);
}
__device__ __forceinline__ f16x4 LO(f16x8 v) { f16x4 r; r[0]=v[0]; r[1]=v[1]; r[2]=v[2]; r[3]=v[3]; return r; }
__device__ __forceinline__ f16x4 HI(f16x8 v) { f16x4 r; r[0]=v[4]; r[1]=v[5]; r[2]=v[6]; r[3]=v[7]; return r; }

// LLC-coherent (sc1) relaxed agent atomics (proven round 9).
__device__ __forceinline__ u64 ld_llc(const u64* p) {
    return __hip_atomic_load(p, __ATOMIC_RELAXED, __HIP_MEMORY_SCOPE_AGENT);
}
__device__ __forceinline__ void st_llc(u64* p, u64 v) {
    __hip_atomic_store(p, v, __ATOMIC_RELAXED, __HIP_MEMORY_SCOPE_AGENT);
}
__device__ __forceinline__ int ld_flag(const int* p) {
    return __hip_atomic_load(p, __ATOMIC_RELAXED, __HIP_MEMORY_SCOPE_AGENT);
}
__device__ __forceinline__ void st_flag(int* p, int v) {
    __hip_atomic_store(p, v, __ATOMIC_RELAXED, __HIP_MEMORY_SCOPE_AGENT);
}
// dual-outstanding monotonic-flag poll: check load N while load N+1 flies.
__device__ __forceinline__ void poll_ge(const int* p, int target) {
    int a = ld_flag(p);
    int b = ld_flag(p);
    while (a < target) { a = b; b = ld_flag(p); }
}

struct P6 {
    const float* s0; const float* s1; const float* s2;
    const float* s3; const float* s4; const float* s5;
};

// ---------------- K_PRE: fused {scalar-LSTM | weight cvt+swizzle | flag zero} --
__global__ __launch_bounds__(256) void k_pre(
    const int* __restrict__ ln, const int* __restrict__ rn,
    const float* __restrict__ tlW, const float* __restrict__ tlU, const float* __restrict__ tlb,
    const float* __restrict__ trW, const float* __restrict__ trU, const float* __restrict__ trb,
    float* __restrict__ states,
    P6 p, f16* __restrict__ wdst,
    int* __restrict__ flags)
{
    const int bid = blockIdx.x;
    const int tid = threadIdx.x;
    if (bid >= 768) {                      // ---- flag zero ----
        int* f = flags + (bid - 768) * 16384;
        for (int i = tid; i < 16384; i += 256) f[i] = 0;
        return;
    }
    if (bid >= 256) {                      // ---- weight cvt ----
        const int base = (bid - 256) * 3072;
#pragma unroll
        for (int k = 0; k < 12; ++k) {
            const int i = base + k * 256 + tid;
            const int seg = i >> 18, d = i & 262143;
            const float* s = seg == 0 ? p.s0 : seg == 1 ? p.s1 : seg == 2 ? p.s2
                           : seg == 3 ? p.s3 : seg == 4 ? p.s4 : p.s5;
            const int e  = d & 7;
            const int fr = (d >> 3) & 15;
            const int fq = (d >> 7) & 3;
            const int ktp = (d >> 9) & 7;
            const int fi = (d >> 12) & 15;
            const int g  = (d >> 16) & 3;
            const int row = g * 256 + fi * 16 + fr;
            const int col = ktp * 32 + (e >> 2) * 16 + fq * 4 + (e & 3);
            wdst[i] = (f16)s[row * 256 + col];
        }
        return;
    }
    // ---- scalar LSTM: 2 chains per block, L0(t) || L1(t-1) pipelined ----
    __shared__ int tok[2][NTIME];
    const int half = tid >> 7, n = tid & 127;
    const int pair = bid * 2 + half;
    const int branch = pair >> 8;
    const int b = pair & 255;
    const int* tp = (branch ? rn : ln) + (size_t)b * (4 * NTIME);  // voice 0
    for (int i = n; i < NTIME; i += 128) tok[half][i] = tp[i];
    __syncthreads();
    const float* W  = branch ? trW : tlW;
    const float* U  = branch ? trU : tlU;
    const float* Bb = branch ? trb : tlb;
    const float u00 = U[0], u01 = U[1], u02 = U[2], u03 = U[3];
    const float f00 = Bb[0], f01 = Bb[1], f02 = Bb[2], f03 = Bb[3];
    const float o00 = f00 + W[0], o01 = f01 + W[1], o02 = f02 + W[2], o03 = f03 + W[3];
    const float w10 = W[4], w11 = W[5], w12 = W[6], w13 = W[7];
    const float u10 = U[4], u11 = U[5], u12 = U[6], u13 = U[7];
    const float b10 = Bb[4], b11 = Bb[5], b12 = Bb[6], b13 = Bb[7];
    float h0 = 0.f, c0 = 0.f, h1 = 0.f, c1 = 0.f;
    {   // L0 step 0
        const bool x = (tok[half][0] == n);
        float pi = fmaf(u00, h0, x ? o00 : f00);
        float pf = fmaf(u01, h0, x ? o01 : f01);
        float pg = fmaf(u02, h0, x ? o02 : f02);
        float po = fmaf(u03, h0, x ? o03 : f03);
        const float ig = sigf(pi), fg = sigf(pf), gg = tanh_f(pg), og = sigf(po);
        c0 = fmaf(fg, c0, ig * gg);
        h0 = og * tanh_f(c0);
    }
    for (int t = 1; t < NTIME; ++t) {
        const bool x = (tok[half][t] == n);
        float api = fmaf(u00, h0, x ? o00 : f00);
        float apf = fmaf(u01, h0, x ? o01 : f01);
        float apg = fmaf(u02, h0, x ? o02 : f02);
        float apo = fmaf(u03, h0, x ? o03 : f03);
        float bpi = fmaf(w10, h0, fmaf(u10, h1, b10));
        float bpf = fmaf(w11, h0, fmaf(u11, h1, b11));
        float bpg = fmaf(w12, h0, fmaf(u12, h1, b12));
        float bpo = fmaf(w13, h0, fmaf(u13, h1, b13));
        const float aig = sigf(api), afg = sigf(apf), agg = tanh_f(apg), aog = sigf(apo);
        const float big = sigf(bpi), bfg = sigf(bpf), bgg = tanh_f(bpg), bog = sigf(bpo);
        c0 = fmaf(afg, c0, aig * agg);
        c1 = fmaf(bfg, c1, big * bgg);
        h0 = aog * tanh_f(c0);
        h1 = bog * tanh_f(c1);
    }
    {   // final L1 step
        float pi = fmaf(w10, h0, fmaf(u10, h1, b10));
        float pf = fmaf(w11, h0, fmaf(u11, h1, b11));
        float pg = fmaf(w12, h0, fmaf(u12, h1, b12));
        float po = fmaf(w13, h0, fmaf(u13, h1, b13));
        const float ig = sigf(pi), fg = sigf(pf), gg = tanh_f(pg), og = sigf(po);
        c1 = fmaf(fg, c1, ig * gg);
        h1 = og * tanh_f(c1);
    }
    states[((size_t)(branch * NBATCH + b)) * NCLS + n] = h1;
}

// ---------------- K2: pipelined L0+L1 recurrence (512 blocks) ----------------
// blocks 0-255: layer 0; blocks 256-511: layer 1 (lag-1 on h0img via flags0).
// 3 barriers/step: compute(+direct LLC af load) -> B -> finish -> B ->
// push+flag || polls -> B. af loaded straight from the LLC image (slot s-1).
__global__ __launch_bounds__(256, 2) void k_rec(
    const float* __restrict__ states,
    const f16* __restrict__ whh0, const f16* __restrict__ whh1,
    const f16* __restrict__ wih1,
    const float* __restrict__ wih0L, const float* __restrict__ wih0R,
    const float* __restrict__ b0L, const float* __restrict__ b0R,
    const float* __restrict__ b1L, const float* __restrict__ b1R,
    f16* __restrict__ h0img,               // [32 group][128 s][4096]
    f16* __restrict__ ring,                // [32 group][4 slot][4096]
    int* __restrict__ flags0,              // [32 group][8] stride 64 ints
    int* __restrict__ flags1,              // [32 group][8] stride 64 ints
    float* __restrict__ h1out)             // [2][256][256] f32
{
    extern __shared__ char smem[];
    f16*   wlds = (f16*)smem;                    // 65536 B weight slice
    f16*   img  = (f16*)(smem + 65536);          // 8192 B push-staging image
    float* cmb  = (float*)(smem + 73728);        // 6144 B  (total 79872)

    const int bid = blockIdx.x;
    const bool isL1 = bid >= 256;
    const int sub = isL1 ? (bid - 256) : bid;
    const int qm = sub >> 5, g = sub & 31;
    const int branch = g >> 4, tb = g & 15;
    const int tid = threadIdx.x;
    const int w = tid >> 6, l = tid & 63, fr = l & 15, fq = l >> 4;

    {   // stage the recurrent weight slice (Whh0 or Whh1): 64 rows x 512 f16
        const f16* base = (isL1 ? whh1 : whh0) + ((size_t)branch << 18);
        for (int c = tid; c < 4096; c += 256) {
            const int rl = c >> 6, coli = c & 63;
            const int gg = rl >> 4, ff = (rl >> 3) & 1, ktp = rl & 7;
            *(uint4*)(wlds + rl * 512 + coli * 8) =
                *(const uint4*)(base + ((size_t)((gg * 16 + qm * 2 + ff) * 8 + ktp) << 9) + coli * 8);
        }
    }
    ((uint4*)img)[tid] = (uint4){0u, 0u, 0u, 0u};
    ((uint4*)img)[tid + 256] = (uint4){0u, 0u, 0u, 0u};

    if (!isL1) {
        // ================= LAYER 0 =================
        const float* bias = branch ? b0R : b0L;
        const float* w0p  = branch ? wih0R : wih0L;
        const int fi_f = qm * 2 + (w < 2 ? w : 0);
        float bv[4], w0v[4];
#pragma unroll
        for (int g4 = 0; g4 < 4; ++g4) {
            bv[g4]  = bias[g4 * 256 + fi_f * 16 + fr];
            w0v[g4] = w0p[g4 * 256 + fi_f * 16 + fr];
        }
        float cst[4] = {0.f, 0.f, 0.f, 0.f};
        f16* gimg = h0img + (size_t)g * (NCLS * 4096);
        int* f0 = flags0 + g * 512;
        __syncthreads();

        for (int s = 0; s < NCLS; ++s) {
            // af = h(s-1): direct LLC load (slot s-1, all 8 chunks); zeros at s=0
            f16x4 af[16];
            if (s == 0) {
#pragma unroll
                for (int kt = 0; kt < 16; ++kt)
                    af[kt] = __builtin_bit_cast(f16x4, 0ull);
            } else {
                const u64* gs = (const u64*)(gimg + (size_t)(s - 1) * 4096) + l;
#pragma unroll
                for (int kt = 0; kt < 16; ++kt)
                    af[kt] = __builtin_bit_cast(f16x4, ld_llc(gs + kt * 64));
            }
            float st[4];
            if (w < 2) {
#pragma unroll
                for (int r = 0; r < 4; ++r)
                    st[r] = states[((size_t)(branch * NBATCH + tb * 16 + fq * 4 + r)) * NCLS + s];
            }
            f32x4 acc[2];
#pragma unroll
            for (int f = 0; f < 2; ++f) {
                f32x4 a0 = {0.f,0.f,0.f,0.f}, a1 = {0.f,0.f,0.f,0.f};
#pragma unroll
                for (int ktp = 0; ktp < 8; ++ktp) {
                    const f16x8 v = *(const f16x8*)(wlds + (((w * 2 + f) * 8 + ktp) << 9) + l * 8);
                    a0 = __builtin_amdgcn_mfma_f32_16x16x16f16(af[2 * ktp],     LO(v), a0, 0, 0, 0);
                    a1 = __builtin_amdgcn_mfma_f32_16x16x16f16(af[2 * ktp + 1], HI(v), a1, 0, 0, 0);
                }
                acc[f] = a0 + a1;
            }
            // publish: e0=(w0,f1) e1=(w1,f0) e2=(w2,f0) e3=(w2,f1) e4=(w3,f0) e5=(w3,f1)
            if (w == 0) {
#pragma unroll
                for (int r = 0; r < 4; ++r) cmb[(0 * 4 + r) * 64 + l] = acc[1][r];
            } else if (w == 1) {
#pragma unroll
                for (int r = 0; r < 4; ++r) cmb[(1 * 4 + r) * 64 + l] = acc[0][r];
            } else if (w == 2) {
#pragma unroll
                for (int r = 0; r < 4; ++r) {
                    cmb[(2 * 4 + r) * 64 + l] = acc[0][r];
                    cmb[(3 * 4 + r) * 64 + l] = acc[1][r];
                }
            } else {
#pragma unroll
                for (int r = 0; r < 4; ++r) {
                    cmb[(4 * 4 + r) * 64 + l] = acc[0][r];
                    cmb[(5 * 4 + r) * 64 + l] = acc[1][r];
                }
            }
            __syncthreads();                // cmb ready
            if (w < 2) {                    // finisher: frag f = w
#pragma unroll
                for (int r = 0; r < 4; ++r) {
                    const float g0 = (w == 0) ? acc[0][r] : cmb[(0 * 4 + r) * 64 + l];
                    const float g1 = (w == 0) ? cmb[(1 * 4 + r) * 64 + l] : acc[1][r];
                    const float g2 = (w == 0) ? cmb[(2 * 4 + r) * 64 + l] : cmb[(3 * 4 + r) * 64 + l];
                    const float g3 = (w == 0) ? cmb[(4 * 4 + r) * 64 + l] : cmb[(5 * 4 + r) * 64 + l];
                    const float pi = fmaf(st[r], w0v[0], g0 + bv[0]);
                    const float pf = fmaf(st[r], w0v[1], g1 + bv[1]);
                    const float pg = fmaf(st[r], w0v[2], g2 + bv[2]);
                    const float po = fmaf(st[r], w0v[3], g3 + bv[3]);
                    const float ig = sigf(pi), fg = sigf(pf), gg = tanh_f(pg), og = sigf(po);
                    cst[r] = fmaf(fg, cst[r], ig * gg);
                    const float hn = og * tanh_f(cst[r]);
                    img[fi_f * 256 + (fq * 4 + r + 16 * (fr >> 2)) * 4 + (fr & 3)] = (f16)hn;
                }
            }
            __syncthreads();                // own 1 KB chunk complete in LDS
            if (w == 0) {                   // push + flag (poll runs on wave 2)
                u64* gd = (u64*)(gimg + (size_t)s * 4096);
                st_llc(gd + qm * 128 + l,      ((const u64*)img)[qm * 128 + l]);
                st_llc(gd + qm * 128 + 64 + l, ((const u64*)img)[qm * 128 + 64 + l]);
                asm volatile("s_waitcnt vmcnt(0)" ::: "memory");
                if (l == 0) st_flag(f0 + qm * 64, s + 1);
            } else if (w == 2 && s < NCLS - 1 && l < 7) {   // concurrent peer poll
                const int p = l + (l >= qm);
                poll_ge(f0 + p * 64, s + 1);
            }
            if (s == NCLS - 1) break;
            __syncthreads();                // peers' slot s ready for next step
        }
    } else {
        // ================= LAYER 1 =================
        const float* bias = branch ? b1R : b1L;
        const int fi_f = qm * 2 + (w < 2 ? w : 0);   // finisher frag (w0->0, w1->1)
        float bv[4];
#pragma unroll
        for (int g4 = 0; g4 < 4; ++g4) bv[g4] = bias[g4 * 256 + fi_f * 16 + fr];
        float cst[4] = {0.f, 0.f, 0.f, 0.f};
        const f16* wstream = wih1 + ((size_t)branch << 18) + l * 8;
        const f16* gimg = h0img + (size_t)g * (NCLS * 4096);
        f16* gring = ring + (size_t)g * (4 * 4096);
        int* f0 = flags0 + g * 512;
        int* f1 = flags1 + g * 512;
        __syncthreads();
        if (w == 3 && l < 8) {              // wait for h0(0) (all 8 producers)
            poll_ge(f0 + l * 64, 1);
        }
        __syncthreads();

        for (int t = 0; t < NCLS; ++t) {
            // af0 = h0(t): direct LLC load (gated by last step's w3 poll)
            f16x4 af0[16];
            {
                const u64* s2 = (const u64*)(gimg + (size_t)t * 4096) + l;
#pragma unroll
                for (int kt = 0; kt < 16; ++kt)
                    af0[kt] = __builtin_bit_cast(f16x4, ld_llc(s2 + kt * 64));
            }
            // af1 = h1(t-1): direct LLC load from ring slot (t-1)&3; zeros at t=0
            f16x4 af1[16];
            if (t == 0) {
#pragma unroll
                for (int kt = 0; kt < 16; ++kt)
                    af1[kt] = __builtin_bit_cast(f16x4, 0ull);
            } else {
                const u64* gs = (const u64*)(gring + (size_t)((t - 1) & 3) * 4096) + l;
#pragma unroll
                for (int kt = 0; kt < 16; ++kt)
                    af1[kt] = __builtin_bit_cast(f16x4, ld_llc(gs + kt * 64));
            }
            // stream Wih1 fragments (loop-invariant rows; L2-resident)
            f16x8 wv[2][8];
#pragma unroll
            for (int f = 0; f < 2; ++f)
#pragma unroll
                for (int ktp = 0; ktp < 8; ++ktp)
                    wv[f][ktp] = *(const f16x8*)(wstream
                        + ((size_t)((w * 16 + qm * 2 + f) * 8 + ktp) << 9));
            f32x4 acc[2];
#pragma unroll
            for (int f = 0; f < 2; ++f) {
                f32x4 a0 = {0.f,0.f,0.f,0.f}, a1 = {0.f,0.f,0.f,0.f};
#pragma unroll
                for (int ktp = 0; ktp < 8; ++ktp) {
                    const f16x8 v = *(const f16x8*)(wlds + (((w * 2 + f) * 8 + ktp) << 9) + l * 8);
                    a0 = __builtin_amdgcn_mfma_f32_16x16x16f16(af1[2 * ktp],     LO(v), a0, 0, 0, 0);
                    a1 = __builtin_amdgcn_mfma_f32_16x16x16f16(af1[2 * ktp + 1], HI(v), a1, 0, 0, 0);
                }
#pragma unroll
                for (int ktp = 0; ktp < 8; ++ktp) {
                    a0 = __builtin_amdgcn_mfma_f32_16x16x16f16(af0[2 * ktp],     LO(wv[f][ktp]), a0, 0, 0, 0);
                    a1 = __builtin_amdgcn_mfma_f32_16x16x16f16(af0[2 * ktp + 1], HI(wv[f][ktp]), a1, 0, 0, 0);
                }
                acc[f] = a0 + a1;
            }
            // publish for split finishers (w0->frag0, w1->frag1):
            // slots: 0=(w1,f0) 1=(w2,f0) 2=(w3,f0) 3=(w0,f1) 4=(w2,f1) 5=(w3,f1)
            if (w == 0) {
#pragma unroll
                for (int r = 0; r < 4; ++r) cmb[(3 * 4 + r) * 64 + l] = acc[1][r];
            } else if (w == 1) {
#pragma unroll
                for (int r = 0; r < 4; ++r) cmb[(0 * 4 + r) * 64 + l] = acc[0][r];
            } else if (w == 2) {
#pragma unroll
                for (int r = 0; r < 4; ++r) {
                    cmb[(1 * 4 + r) * 64 + l] = acc[0][r];
                    cmb[(4 * 4 + r) * 64 + l] = acc[1][r];
                }
            } else {
#pragma unroll
                for (int r = 0; r < 4; ++r) {
                    cmb[(2 * 4 + r) * 64 + l] = acc[0][r];
                    cmb[(5 * 4 + r) * 64 + l] = acc[1][r];
                }
            }
            __syncthreads();                // cmb ready
            if (w < 2) {                    // finisher: frag f = w
#pragma unroll
                for (int r = 0; r < 4; ++r) {
                    const float g0 = (w == 0) ? acc[0][r] : cmb[(3 * 4 + r) * 64 + l];
                    const float g1 = (w == 0) ? cmb[(0 * 4 + r) * 64 + l] : acc[1][r];
                    const float g2 = (w == 0) ? cmb[(1 * 4 + r) * 64 + l] : cmb[(4 * 4 + r) * 64 + l];
                    const float g3 = (w == 0) ? cmb[(2 * 4 + r) * 64 + l] : cmb[(5 * 4 + r) * 64 + l];
                    const float pi = g0 + bv[0];
                    const float pf = g1 + bv[1];
                    const float pg = g2 + bv[2];
                    const float po = g3 + bv[3];
                    const float ig = sigf(pi), fg = sigf(pf), gg = tanh_f(pg), og = sigf(po);
                    cst[r] = fmaf(fg, cst[r], ig * gg);
                    const float hn = og * tanh_f(cst[r]);
                    if (t == NCLS - 1)
                        h1out[((size_t)(branch * NBATCH + tb * 16 + fq * 4 + r)) * NHID
                              + fi_f * 16 + fr] = hn;
                    else
                        img[fi_f * 256 + (fq * 4 + r + 16 * (fr >> 2)) * 4 + (fr & 3)] = (f16)hn;
                }
            }
            if (t == NCLS - 1) break;
            __syncthreads();                // own 1 KB chunk complete in LDS
            f16* slot = gring + (size_t)(t & 3) * 4096;
            if (w == 0) {                   // push + flag (polls run on waves 2/3)
                u64* gd = (u64*)slot;
                st_llc(gd + qm * 128 + l,      ((const u64*)img)[qm * 128 + l]);
                st_llc(gd + qm * 128 + 64 + l, ((const u64*)img)[qm * 128 + 64 + l]);
                asm volatile("s_waitcnt vmcnt(0)" ::: "memory");
                if (l == 0) st_flag(f1 + qm * 64, t + 1);
            } else if (w == 2 && l < 7) {   // concurrent peer h1 poll
                const int p = l + (l >= qm);
                poll_ge(f1 + p * 64, t + 1);
            } else if (w == 3 && l < 8) {   // concurrent h0(t+1) poll (monotonic)
                poll_ge(f0 + l * 64, t + 2);
            }
            __syncthreads();                // peers + h0(t+1) ready for next step
        }
    }
}

// ---------------- K4: MLP head (2H -> 200 -> 128), f32 ------------------------
__global__ __launch_bounds__(256) void k_mlp(
    const float* __restrict__ h1all,   // [2][256][256]
    const float* __restrict__ W1, const float* __restrict__ b1,
    const float* __restrict__ W2, const float* __restrict__ b2,
    float* __restrict__ out)
{
    __shared__ float hrow[512];
    __shared__ float hid[200];
    const int b = blockIdx.x, tid = threadIdx.x;
    hrow[tid]       = h1all[(size_t)b * NHID + tid];
    hrow[256 + tid] = h1all[(size_t)(NBATCH + b) * NHID + tid];
    __syncthreads();
    if (tid < 200) {
        float a = b1[tid];
        const float* wr = W1 + (size_t)tid * 512;
        for (int k = 0; k < 512; ++k) a = fmaf(wr[k], hrow[k], a);
        hid[tid] = fmaxf(a, 0.f);
    }
    __syncthreads();
    if (tid < 128) {
        float a = b2[tid];
        const float* wr = W2 + (size_t)tid * 200;
        for (int j = 0; j < 200; ++j) a = fmaf(wr[j], hid[j], a);
        out[(size_t)b * 128 + tid] = a;
    }
}

// ---------------- launch ------------------------------------------------------
extern "C" void kernel_launch(void* const* d_in, const int* in_sizes, int n_in,
                              void* d_out, int out_size, void* d_ws, size_t ws_size,
                              hipStream_t stream)
{
    (void)in_sizes; (void)n_in; (void)out_size; (void)ws_size;
    const int*   ln    = (const int*)d_in[0];
    const int*   rn    = (const int*)d_in[2];
    const float* tlW   = (const float*)d_in[4];
    const float* tlU   = (const float*)d_in[5];
    const float* tlb   = (const float*)d_in[6];
    const float* trW   = (const float*)d_in[7];
    const float* trU   = (const float*)d_in[8];
    const float* trb   = (const float*)d_in[9];
    const float* wih0L = (const float*)d_in[10];
    const float* b0L   = (const float*)d_in[12];
    const float* b1L   = (const float*)d_in[15];
    const float* wih0R = (const float*)d_in[16];
    const float* b0R   = (const float*)d_in[18];
    const float* b1R   = (const float*)d_in[21];
    const float* mW1   = (const float*)d_in[22];
    const float* mb1   = (const float*)d_in[23];
    const float* mW2   = (const float*)d_in[24];
    const float* mb2   = (const float*)d_in[25];

    // workspace layout (bytes)
    char* ws = (char*)d_ws;
    f16*   w16    = (f16*)ws;                        // 3 MB swizzled weights
    float* states = (float*)(ws + 3145728);          // 256 KB
    float* h1out  = (float*)(ws + 3407872);          // 512 KB
    int*   flags  = (int*)(ws + 3932160);            // 128 KB (2 x 32 x 8 x 64 ints)
    f16*   ring   = (f16*)(ws + 4063232);            // 1 MB (32 x 4 x 4096 f16)
    f16*   h0img  = (f16*)(ws + 5111808);            // 32 MB (32 x 128 x 4096 f16)

    f16* whh0 = w16;
    f16* whh1 = w16 + 2 * 262144;
    f16* wih1 = w16 + 4 * 262144;
    int* flags0 = flags;
    int* flags1 = flags + 16384;

    (void)hipFuncSetAttribute(reinterpret_cast<const void*>(k_rec),
                              hipFuncAttributeMaxDynamicSharedMemorySize, 79872);

    P6 p { (const float*)d_in[11], (const float*)d_in[17],   // nl_Whh0, nr_Whh0
           (const float*)d_in[14], (const float*)d_in[20],   // nl_Whh1, nr_Whh1
           (const float*)d_in[13], (const float*)d_in[19] }; // nl_Wih1, nr_Wih1
    k_pre<<<770, 256, 0, stream>>>(ln, rn, tlW, tlU, tlb, trW, trU, trb,
                                   states, p, w16, flags);
    k_rec<<<512, 256, 79872, stream>>>(states, whh0, whh1, wih1, wih0L, wih0R,
                                       b0L, b0R, b1L, b1R, h0img, ring,
                                       flags0, flags1, h1out);
    k_mlp<<<256, 256, 0, stream>>>(h1out, mW1, mb1, mW2, mb2, (float*)d_out);
}